// Round 1
// baseline (11420.557 us; speedup 1.0000x reference)
//
#include <hip/hip_runtime.h>
#include <math.h>

#define HH 480
#define WW 600
#define NN (HH*WW)      // 288000
#define PP 2048
#define H2 240
#define W2 300
#define N2 (H2*W2)      // 72000

// ---- workspace layout (in floats) ----
// [0]           : depth sum
// [16  .. 48)   : gn1 stats (sum[16], sumsq[16])
// [64  .. 96)   : gn2 stats
// [112 ..144)   : gn3 stats
// [160 ..192)   : gn4 stats
#define X_OFF   256
#define C1_OFF  (X_OFF + 3*NN)
#define D1_OFF  (C1_OFF + 32*NN)
#define BM_OFF  (D1_OFF + 64*N2)
#define FT_OFF  (BM_OFF + 64*N2)
// total = 256 + 864000 + 9216000 + 4608000 + 4608000 + 18432000 floats ≈ 151 MB

// ---------------- depth mean ----------------
__global__ void k_sum(const float* __restrict__ d, float* __restrict__ ws) {
    float s = 0.f;
    for (int i = blockIdx.x*blockDim.x + threadIdx.x; i < NN; i += gridDim.x*blockDim.x)
        s += d[i];
    #pragma unroll
    for (int o = 32; o; o >>= 1) s += __shfl_down(s, o, 64);
    __shared__ float sm[4];
    int wid = threadIdx.x >> 6;
    if ((threadIdx.x & 63) == 0) sm[wid] = s;
    __syncthreads();
    if (threadIdx.x == 0) {
        float t = 0.f;
        int nw = blockDim.x >> 6;
        for (int w = 0; w < nw; ++w) t += sm[w];
        atomicAdd(ws, t);
    }
}

// ---------------- build x = [std_depth, mask, attn(0)] ----------------
__global__ void k_buildx(const float* __restrict__ depth, const float* __restrict__ mask,
                         const float* __restrict__ ws, float* __restrict__ x) {
    int i = blockIdx.x*blockDim.x + threadIdx.x;
    if (i >= NN) return;
    float mean = ws[0] * (1.0f/NN);
    x[i]        = (depth[i] - mean) * 10.0f;
    x[NN + i]   = mask[i];
    x[2*NN + i] = 0.f;
}

__global__ void k_scatter(const int* __restrict__ pairs, float* __restrict__ x) {
    int p = blockIdx.x*blockDim.x + threadIdx.x;
    if (p < PP) x[2*NN + pairs[2*p]] = 1.0f;
}

// ---------------- direct 3x3 conv (SAME) ----------------
// PT = pad_low (same for h and w). stride1: PT=1; stride2 (480->240): PT=0.
template<int CIN, int STRIDE, int PT>
__global__ void k_conv(const float* __restrict__ in, const float* __restrict__ w,
                       const float* __restrict__ bias, float* __restrict__ out,
                       int Hi, int Wi, int Ho, int Wo) {
    int x  = blockIdx.x*blockDim.x + threadIdx.x;
    int y  = blockIdx.y;
    int co = blockIdx.z;
    if (x >= Wo) return;
    const float* wp = w + co*CIN*9;
    float acc = bias[co];
    for (int ci = 0; ci < CIN; ++ci) {
        const float* ip = in + ci*Hi*Wi;
        #pragma unroll
        for (int dy = 0; dy < 3; ++dy) {
            int iy = y*STRIDE + dy - PT;
            if ((unsigned)iy < (unsigned)Hi) {
                const float* rp = ip + iy*Wi;
                #pragma unroll
                for (int dx = 0; dx < 3; ++dx) {
                    int ix = x*STRIDE + dx - PT;
                    if ((unsigned)ix < (unsigned)Wi)
                        acc += rp[ix] * wp[(ci*3+dy)*3+dx];
                }
            }
        }
    }
    out[(co*Ho + y)*Wo + x] = acc;
}

// ---------------- conv4: virtual concat( upsample2x(bm), c1 ), 96->64 ----------------
__global__ void k_conv4(const float* __restrict__ bm, const float* __restrict__ c1,
                        const float* __restrict__ w, const float* __restrict__ bias,
                        float* __restrict__ out) {
    int x  = blockIdx.x*blockDim.x + threadIdx.x;
    int y  = blockIdx.y;
    int co = blockIdx.z;
    if (x >= WW) return;
    const float* wp = w + co*96*9;
    float acc = bias[co];
    // channels 0..63: nearest-upsampled bm
    for (int ci = 0; ci < 64; ++ci) {
        const float* ip = bm + ci*N2;
        #pragma unroll
        for (int dy = 0; dy < 3; ++dy) {
            int iy = y + dy - 1;
            if ((unsigned)iy < (unsigned)HH) {
                const float* rp = ip + (iy>>1)*W2;
                #pragma unroll
                for (int dx = 0; dx < 3; ++dx) {
                    int ix = x + dx - 1;
                    if ((unsigned)ix < (unsigned)WW)
                        acc += rp[ix>>1] * wp[(ci*3+dy)*3+dx];
                }
            }
        }
    }
    // channels 64..95: c1
    for (int ci = 0; ci < 32; ++ci) {
        const float* ip = c1 + ci*NN;
        #pragma unroll
        for (int dy = 0; dy < 3; ++dy) {
            int iy = y + dy - 1;
            if ((unsigned)iy < (unsigned)HH) {
                const float* rp = ip + iy*WW;
                #pragma unroll
                for (int dx = 0; dx < 3; ++dx) {
                    int ix = x + dx - 1;
                    if ((unsigned)ix < (unsigned)WW)
                        acc += rp[ix] * wp[((64+ci)*3+dy)*3+dx];
                }
            }
        }
    }
    out[(co*HH + y)*WW + x] = acc;
}

// ---------------- group norm (16 groups): stats then apply+lrelu ----------------
__global__ void k_gnstats(const float* __restrict__ x, int elems_per_group,
                          float* __restrict__ stat) {
    int g = blockIdx.y;
    const float* p = x + (long)g*elems_per_group;
    float s = 0.f, s2 = 0.f;
    for (int i = blockIdx.x*blockDim.x + threadIdx.x; i < elems_per_group; i += gridDim.x*blockDim.x) {
        float v = p[i]; s += v; s2 += v*v;
    }
    #pragma unroll
    for (int o = 32; o; o >>= 1) { s += __shfl_down(s,o,64); s2 += __shfl_down(s2,o,64); }
    __shared__ float sm[4], sm2[4];
    int wid = threadIdx.x >> 6;
    if ((threadIdx.x & 63) == 0) { sm[wid]=s; sm2[wid]=s2; }
    __syncthreads();
    if (threadIdx.x == 0) {
        float t=0.f, t2=0.f;
        int nw = blockDim.x >> 6;
        for (int i = 0; i < nw; ++i) { t += sm[i]; t2 += sm2[i]; }
        atomicAdd(&stat[g], t);
        atomicAdd(&stat[16+g], t2);
    }
}

__global__ void k_gnapply(float* __restrict__ x, const float* __restrict__ scale,
                          const float* __restrict__ bias, const float* __restrict__ stat,
                          int HW, int chper, int total) {
    int i = blockIdx.x*blockDim.x + threadIdx.x;
    if (i >= total) return;
    int c = i / HW;
    int g = c / chper;
    float cnt = (float)chper * (float)HW;
    float mu  = stat[g] / cnt;
    float var = stat[16+g] / cnt - mu*mu;
    float rs  = rsqrtf(var + 1e-5f);
    float v = (x[i] - mu) * rs * scale[c] + bias[c];
    x[i] = v >= 0.f ? v : 0.2f*v;
}

// ---------------- gather + MLP head ----------------
__global__ void k_mlp(const float* __restrict__ pose, const float* __restrict__ sd,
                      const int* __restrict__ pairs, const float* __restrict__ feats,
                      const float* __restrict__ gw, const float* __restrict__ gb,
                      const float* __restrict__ hw, const float* __restrict__ hb,
                      const float* __restrict__ ow, const float* __restrict__ ob,
                      float* __restrict__ out) {
    int wid  = threadIdx.x >> 6;
    int lane = threadIdx.x & 63;
    int t = blockIdx.x*4 + wid;          // item in [0, 2P)
    int p = t >> 1;
    const float* pp = pose + t*8;
    float q0=pp[0], q1=pp[1], q2=pp[2], q3=pp[3];
    float f0=pp[4], f1=pp[5], f2=pp[6], tr=pp[7];
    int idx = pairs[2*p];
    float dg = sd[idx];
    float cond[15] = {q0*q0,q0*q1,q0*q2,q0*q3,q1*q1,q1*q2,q1*q3,q2*q2,q2*q3,q3*q3,
                      f0,f1,f2,tr,dg};
    float acc = gb[lane];
    #pragma unroll
    for (int k = 0; k < 15; ++k) acc += cond[k]*gw[k*64+lane];
    float gate = 1.f/(1.f+expf(-acc));
    float fg = feats[lane*NN + idx];
    float h = fg*gate;
    float ss = h*h;
    #pragma unroll
    for (int o = 32; o; o >>= 1) ss += __shfl_xor(ss, o, 64);
    h *= rsqrtf(ss + 1e-8f);
    __shared__ float hs[4][64];
    hs[wid][lane] = h;
    __syncthreads();
    float a2 = hb[lane];
    #pragma unroll 8
    for (int d = 0; d < 64; ++d) a2 += hs[wid][d]*hw[d*64+lane];
    float h2 = a2 >= 0.f ? a2 : 0.2f*a2;
    float si = h2 / (1.f+expf(-h2));     // silu
    float v = si * ow[lane];
    #pragma unroll
    for (int o = 32; o; o >>= 1) v += __shfl_xor(v, o, 64);
    if (lane == 0) out[t] = v + ob[0];
}

extern "C" void kernel_launch(void* const* d_in, const int* in_sizes, int n_in,
                              void* d_out, int out_size, void* d_ws, size_t ws_size,
                              hipStream_t stream) {
    const float* depth = (const float*)d_in[0];
    const float* pose  = (const float*)d_in[1];
    const float* mask  = (const float*)d_in[2];
    const int*   pairs = (const int*)  d_in[3];
    const float* c1w = (const float*)d_in[4];  const float* c1b = (const float*)d_in[5];
    const float* g1s = (const float*)d_in[6];  const float* g1b = (const float*)d_in[7];
    const float* c2w = (const float*)d_in[8];  const float* c2b = (const float*)d_in[9];
    const float* g2s = (const float*)d_in[10]; const float* g2b = (const float*)d_in[11];
    const float* c3w = (const float*)d_in[12]; const float* c3b = (const float*)d_in[13];
    const float* g3s = (const float*)d_in[14]; const float* g3b = (const float*)d_in[15];
    const float* c4w = (const float*)d_in[16]; const float* c4b = (const float*)d_in[17];
    const float* g4s = (const float*)d_in[18]; const float* g4b = (const float*)d_in[19];
    const float* gw  = (const float*)d_in[20]; const float* gb  = (const float*)d_in[21];
    const float* hw_ = (const float*)d_in[22]; const float* hb  = (const float*)d_in[23];
    const float* ow  = (const float*)d_in[24]; const float* ob  = (const float*)d_in[25];

    float* ws = (float*)d_ws;
    float* X  = ws + X_OFF;
    float* C1 = ws + C1_OFF;
    float* D1 = ws + D1_OFF;
    float* BM = ws + BM_OFF;
    float* FT = ws + FT_OFF;
    float* st1 = ws + 16;
    float* st2 = ws + 64;
    float* st3 = ws + 112;
    float* st4 = ws + 160;

    hipMemsetAsync(d_ws, 0, 256*sizeof(float), stream);

    k_sum    <<<1024, 256, 0, stream>>>(depth, ws);
    k_buildx <<<(NN+255)/256, 256, 0, stream>>>(depth, mask, ws, X);
    k_scatter<<<(PP+255)/256, 256, 0, stream>>>(pairs, X);

    dim3 cb(128);
    // conv1: 3->32, 480x600
    k_conv<3,1,1><<<dim3((WW+127)/128, HH, 32), cb, 0, stream>>>(X, c1w, c1b, C1, HH, WW, HH, WW);
    k_gnstats<<<dim3(64,16), 256, 0, stream>>>(C1, 2*NN, st1);
    k_gnapply<<<(32*NN+255)/256, 256, 0, stream>>>(C1, g1s, g1b, st1, NN, 2, 32*NN);

    // conv2: 32->64, stride2 -> 240x300
    k_conv<32,2,0><<<dim3((W2+127)/128, H2, 64), cb, 0, stream>>>(C1, c2w, c2b, D1, HH, WW, H2, W2);
    k_gnstats<<<dim3(64,16), 256, 0, stream>>>(D1, 4*N2, st2);
    k_gnapply<<<(64*N2+255)/256, 256, 0, stream>>>(D1, g2s, g2b, st2, N2, 4, 64*N2);

    // conv3: 64->64, 240x300
    k_conv<64,1,1><<<dim3((W2+127)/128, H2, 64), cb, 0, stream>>>(D1, c3w, c3b, BM, H2, W2, H2, W2);
    k_gnstats<<<dim3(64,16), 256, 0, stream>>>(BM, 4*N2, st3);
    k_gnapply<<<(64*N2+255)/256, 256, 0, stream>>>(BM, g3s, g3b, st3, N2, 4, 64*N2);

    // conv4: concat(up(bm), c1) 96->64, 480x600
    k_conv4<<<dim3((WW+127)/128, HH, 64), cb, 0, stream>>>(BM, C1, c4w, c4b, FT);
    k_gnstats<<<dim3(64,16), 256, 0, stream>>>(FT, 4*NN, st4);
    k_gnapply<<<(64*NN+255)/256, 256, 0, stream>>>(FT, g4s, g4b, st4, NN, 4, 64*NN);

    // gather + MLP head: 2P items, one wave each
    k_mlp<<<(2*PP)/4, 256, 0, stream>>>(pose, X, pairs, FT,
                                        gw, gb, hw_, hb, ow, ob, (float*)d_out);
}

// Round 2
// 1308.178 us; speedup vs baseline: 8.7301x; 8.7301x over previous
//
#include <hip/hip_runtime.h>
#include <math.h>

#define HH 480
#define WW 600
#define NN (HH*WW)      // 288000
#define PP 2048
#define H2 240
#define W2 300
#define N2 (H2*W2)      // 72000

// ---- workspace layout (in floats) ----
#define X_OFF   256
#define C1_OFF  (X_OFF + 3*NN)
#define D1_OFF  (C1_OFF + 32*NN)
#define BM_OFF  (D1_OFF + 64*N2)
#define FT_OFF  (BM_OFF + 64*N2)

// ---------------- depth mean ----------------
__global__ void k_sum(const float* __restrict__ d, float* __restrict__ ws) {
    float s = 0.f;
    for (int i = blockIdx.x*blockDim.x + threadIdx.x; i < NN; i += gridDim.x*blockDim.x)
        s += d[i];
    #pragma unroll
    for (int o = 32; o; o >>= 1) s += __shfl_down(s, o, 64);
    __shared__ float sm[4];
    int wid = threadIdx.x >> 6;
    if ((threadIdx.x & 63) == 0) sm[wid] = s;
    __syncthreads();
    if (threadIdx.x == 0) {
        float t = 0.f;
        int nw = blockDim.x >> 6;
        for (int w = 0; w < nw; ++w) t += sm[w];
        atomicAdd(ws, t);
    }
}

// ---------------- build x = [std_depth, mask, attn(0)] ----------------
__global__ void k_buildx(const float* __restrict__ depth, const float* __restrict__ mask,
                         const float* __restrict__ ws, float* __restrict__ x) {
    int i = blockIdx.x*blockDim.x + threadIdx.x;
    if (i >= NN) return;
    float mean = ws[0] * (1.0f/NN);
    x[i]        = (depth[i] - mean) * 10.0f;
    x[NN + i]   = mask[i];
    x[2*NN + i] = 0.f;
}

__global__ void k_scatter(const int* __restrict__ pairs, float* __restrict__ x) {
    int p = blockIdx.x*blockDim.x + threadIdx.x;
    if (p < PP) x[2*NN + pairs[2*p]] = 1.0f;
}

// ---------------- tiled direct 3x3 conv: 1 pixel x TCO couts per thread --------
// Weights are wave-uniform -> scalar loads. Input taps reused across TCO.
template<int CIN, int STRIDE, int PT, int TCO>
__global__ __launch_bounds__(64) void k_conv_t(const float* __restrict__ in,
        const float* __restrict__ w, const float* __restrict__ bias,
        float* __restrict__ out, int Hi, int Wi, int Ho, int Wo) {
    int x   = blockIdx.x*64 + threadIdx.x;
    int y   = blockIdx.y;
    int co0 = blockIdx.z*TCO;
    if (x >= Wo) return;
    float acc[TCO];
    #pragma unroll
    for (int c = 0; c < TCO; ++c) acc[c] = bias[co0+c];
    int  xb   = x*STRIDE - PT;
    bool xint = (xb >= 0) && (xb + 2 < Wi);
    for (int ci = 0; ci < CIN; ++ci) {
        const float* ip = in + (long)ci*Hi*Wi;
        float iv[3][3];
        #pragma unroll
        for (int dy = 0; dy < 3; ++dy) {
            int iy = y*STRIDE + dy - PT;
            if ((unsigned)iy < (unsigned)Hi) {
                const float* rp = ip + (long)iy*Wi + xb;
                if (xint) {
                    iv[dy][0] = rp[0]; iv[dy][1] = rp[1]; iv[dy][2] = rp[2];
                } else {
                    #pragma unroll
                    for (int dx = 0; dx < 3; ++dx) {
                        int ix = xb + dx;
                        iv[dy][dx] = ((unsigned)ix < (unsigned)Wi) ? ip[(long)iy*Wi+ix] : 0.f;
                    }
                }
            } else {
                iv[dy][0] = iv[dy][1] = iv[dy][2] = 0.f;
            }
        }
        const float* wp = w + ((long)co0*CIN + ci)*9;   // uniform -> s_load
        #pragma unroll
        for (int c = 0; c < TCO; ++c) {
            #pragma unroll
            for (int k = 0; k < 9; ++k)
                acc[c] += iv[k/3][k%3] * wp[(long)c*CIN*9 + k];
        }
    }
    #pragma unroll
    for (int c = 0; c < TCO; ++c)
        out[((long)(co0+c)*Ho + y)*Wo + x] = acc[c];
}

// ---------------- conv4: virtual concat( upsample2x(bm), c1 ), 96->64 ----------
template<int TCO>
__global__ __launch_bounds__(64) void k_conv4_t(const float* __restrict__ bm,
        const float* __restrict__ c1, const float* __restrict__ w,
        const float* __restrict__ bias, float* __restrict__ out) {
    int x   = blockIdx.x*64 + threadIdx.x;
    int y   = blockIdx.y;
    int co0 = blockIdx.z*TCO;
    if (x >= WW) return;
    float acc[TCO];
    #pragma unroll
    for (int c = 0; c < TCO; ++c) acc[c] = bias[co0+c];
    int  xb   = x - 1;
    bool xint = (xb >= 0) && (xb + 2 < WW);
    // part A: ci 0..63 = nearest-upsampled bm (240x300 source)
    for (int ci = 0; ci < 64; ++ci) {
        const float* ip = bm + (long)ci*N2;
        float iv[3][3];
        #pragma unroll
        for (int dy = 0; dy < 3; ++dy) {
            int iy = y + dy - 1;
            if ((unsigned)iy < (unsigned)HH) {
                const float* rp = ip + (long)(iy>>1)*W2;
                if (xint) {
                    iv[dy][0] = rp[xb>>1]; iv[dy][1] = rp[(xb+1)>>1]; iv[dy][2] = rp[(xb+2)>>1];
                } else {
                    #pragma unroll
                    for (int dx = 0; dx < 3; ++dx) {
                        int ix = xb + dx;
                        iv[dy][dx] = ((unsigned)ix < (unsigned)WW) ? rp[ix>>1] : 0.f;
                    }
                }
            } else {
                iv[dy][0] = iv[dy][1] = iv[dy][2] = 0.f;
            }
        }
        const float* wp = w + ((long)co0*96 + ci)*9;
        #pragma unroll
        for (int c = 0; c < TCO; ++c) {
            #pragma unroll
            for (int k = 0; k < 9; ++k)
                acc[c] += iv[k/3][k%3] * wp[(long)c*96*9 + k];
        }
    }
    // part B: ci 64..95 = c1 (480x600)
    for (int ci = 0; ci < 32; ++ci) {
        const float* ip = c1 + (long)ci*NN;
        float iv[3][3];
        #pragma unroll
        for (int dy = 0; dy < 3; ++dy) {
            int iy = y + dy - 1;
            if ((unsigned)iy < (unsigned)HH) {
                const float* rp = ip + (long)iy*WW + xb;
                if (xint) {
                    iv[dy][0] = rp[0]; iv[dy][1] = rp[1]; iv[dy][2] = rp[2];
                } else {
                    #pragma unroll
                    for (int dx = 0; dx < 3; ++dx) {
                        int ix = xb + dx;
                        iv[dy][dx] = ((unsigned)ix < (unsigned)WW) ? ip[(long)iy*WW+ix] : 0.f;
                    }
                }
            } else {
                iv[dy][0] = iv[dy][1] = iv[dy][2] = 0.f;
            }
        }
        const float* wp = w + ((long)co0*96 + 64 + ci)*9;
        #pragma unroll
        for (int c = 0; c < TCO; ++c) {
            #pragma unroll
            for (int k = 0; k < 9; ++k)
                acc[c] += iv[k/3][k%3] * wp[(long)c*96*9 + k];
        }
    }
    #pragma unroll
    for (int c = 0; c < TCO; ++c)
        out[((long)(co0+c)*HH + y)*WW + x] = acc[c];
}

// ---------------- group norm (16 groups): stats then apply+lrelu ----------------
__global__ void k_gnstats(const float* __restrict__ x, int elems_per_group,
                          float* __restrict__ stat) {
    int g = blockIdx.y;
    const float* p = x + (long)g*elems_per_group;
    float s = 0.f, s2 = 0.f;
    for (int i = blockIdx.x*blockDim.x + threadIdx.x; i < elems_per_group; i += gridDim.x*blockDim.x) {
        float v = p[i]; s += v; s2 += v*v;
    }
    #pragma unroll
    for (int o = 32; o; o >>= 1) { s += __shfl_down(s,o,64); s2 += __shfl_down(s2,o,64); }
    __shared__ float sm[4], sm2[4];
    int wid = threadIdx.x >> 6;
    if ((threadIdx.x & 63) == 0) { sm[wid]=s; sm2[wid]=s2; }
    __syncthreads();
    if (threadIdx.x == 0) {
        float t=0.f, t2=0.f;
        int nw = blockDim.x >> 6;
        for (int i = 0; i < nw; ++i) { t += sm[i]; t2 += sm2[i]; }
        atomicAdd(&stat[g], t);
        atomicAdd(&stat[16+g], t2);
    }
}

__global__ void k_gnapply(float* __restrict__ x, const float* __restrict__ scale,
                          const float* __restrict__ bias, const float* __restrict__ stat,
                          int HW, int chper, int total) {
    int i = blockIdx.x*blockDim.x + threadIdx.x;
    if (i >= total) return;
    int c = i / HW;
    int g = c / chper;
    float cnt = (float)chper * (float)HW;
    float mu  = stat[g] / cnt;
    float var = stat[16+g] / cnt - mu*mu;
    float rs  = rsqrtf(var + 1e-5f);
    float v = (x[i] - mu) * rs * scale[c] + bias[c];
    x[i] = v >= 0.f ? v : 0.2f*v;
}

// ---------------- gather + MLP head ----------------
__global__ void k_mlp(const float* __restrict__ pose, const float* __restrict__ sd,
                      const int* __restrict__ pairs, const float* __restrict__ feats,
                      const float* __restrict__ gw, const float* __restrict__ gb,
                      const float* __restrict__ hw, const float* __restrict__ hb,
                      const float* __restrict__ ow, const float* __restrict__ ob,
                      float* __restrict__ out) {
    int wid  = threadIdx.x >> 6;
    int lane = threadIdx.x & 63;
    int t = blockIdx.x*4 + wid;          // item in [0, 2P)
    int p = t >> 1;
    const float* pp = pose + t*8;
    float q0=pp[0], q1=pp[1], q2=pp[2], q3=pp[3];
    float f0=pp[4], f1=pp[5], f2=pp[6], tr=pp[7];
    int idx = pairs[2*p];
    float dg = sd[idx];
    float cond[15] = {q0*q0,q0*q1,q0*q2,q0*q3,q1*q1,q1*q2,q1*q3,q2*q2,q2*q3,q3*q3,
                      f0,f1,f2,tr,dg};
    float acc = gb[lane];
    #pragma unroll
    for (int k = 0; k < 15; ++k) acc += cond[k]*gw[k*64+lane];
    float gate = 1.f/(1.f+expf(-acc));
    float fg = feats[(long)lane*NN + idx];
    float h = fg*gate;
    float ss = h*h;
    #pragma unroll
    for (int o = 32; o; o >>= 1) ss += __shfl_xor(ss, o, 64);
    h *= rsqrtf(ss + 1e-8f);
    __shared__ float hs[4][64];
    hs[wid][lane] = h;
    __syncthreads();
    float a2 = hb[lane];
    #pragma unroll 8
    for (int d = 0; d < 64; ++d) a2 += hs[wid][d]*hw[d*64+lane];
    float h2 = a2 >= 0.f ? a2 : 0.2f*a2;
    float si = h2 / (1.f+expf(-h2));     // silu
    float v = si * ow[lane];
    #pragma unroll
    for (int o = 32; o; o >>= 1) v += __shfl_xor(v, o, 64);
    if (lane == 0) out[t] = v + ob[0];
}

extern "C" void kernel_launch(void* const* d_in, const int* in_sizes, int n_in,
                              void* d_out, int out_size, void* d_ws, size_t ws_size,
                              hipStream_t stream) {
    const float* depth = (const float*)d_in[0];
    const float* pose  = (const float*)d_in[1];
    const float* mask  = (const float*)d_in[2];
    const int*   pairs = (const int*)  d_in[3];
    const float* c1w = (const float*)d_in[4];  const float* c1b = (const float*)d_in[5];
    const float* g1s = (const float*)d_in[6];  const float* g1b = (const float*)d_in[7];
    const float* c2w = (const float*)d_in[8];  const float* c2b = (const float*)d_in[9];
    const float* g2s = (const float*)d_in[10]; const float* g2b = (const float*)d_in[11];
    const float* c3w = (const float*)d_in[12]; const float* c3b = (const float*)d_in[13];
    const float* g3s = (const float*)d_in[14]; const float* g3b = (const float*)d_in[15];
    const float* c4w = (const float*)d_in[16]; const float* c4b = (const float*)d_in[17];
    const float* g4s = (const float*)d_in[18]; const float* g4b = (const float*)d_in[19];
    const float* gw  = (const float*)d_in[20]; const float* gb  = (const float*)d_in[21];
    const float* hw_ = (const float*)d_in[22]; const float* hb  = (const float*)d_in[23];
    const float* ow  = (const float*)d_in[24]; const float* ob  = (const float*)d_in[25];

    float* ws = (float*)d_ws;
    float* X  = ws + X_OFF;
    float* C1 = ws + C1_OFF;
    float* D1 = ws + D1_OFF;
    float* BM = ws + BM_OFF;
    float* FT = ws + FT_OFF;
    float* st1 = ws + 16;
    float* st2 = ws + 64;
    float* st3 = ws + 112;
    float* st4 = ws + 160;

    hipMemsetAsync(d_ws, 0, 256*sizeof(float), stream);

    k_sum    <<<1024, 256, 0, stream>>>(depth, ws);
    k_buildx <<<(NN+255)/256, 256, 0, stream>>>(depth, mask, ws, X);
    k_scatter<<<(PP+255)/256, 256, 0, stream>>>(pairs, X);

    // conv1: 3->32, 480x600
    k_conv_t<3,1,1,16><<<dim3(10, HH, 2), 64, 0, stream>>>(X, c1w, c1b, C1, HH, WW, HH, WW);
    k_gnstats<<<dim3(64,16), 256, 0, stream>>>(C1, 2*NN, st1);
    k_gnapply<<<(32*NN+255)/256, 256, 0, stream>>>(C1, g1s, g1b, st1, NN, 2, 32*NN);

    // conv2: 32->64, stride2 -> 240x300
    k_conv_t<32,2,0,16><<<dim3(5, H2, 4), 64, 0, stream>>>(C1, c2w, c2b, D1, HH, WW, H2, W2);
    k_gnstats<<<dim3(64,16), 256, 0, stream>>>(D1, 4*N2, st2);
    k_gnapply<<<(64*N2+255)/256, 256, 0, stream>>>(D1, g2s, g2b, st2, N2, 4, 64*N2);

    // conv3: 64->64, 240x300
    k_conv_t<64,1,1,16><<<dim3(5, H2, 4), 64, 0, stream>>>(D1, c3w, c3b, BM, H2, W2, H2, W2);
    k_gnstats<<<dim3(64,16), 256, 0, stream>>>(BM, 4*N2, st3);
    k_gnapply<<<(64*N2+255)/256, 256, 0, stream>>>(BM, g3s, g3b, st3, N2, 4, 64*N2);

    // conv4: concat(up(bm), c1) 96->64, 480x600
    k_conv4_t<16><<<dim3(10, HH, 4), 64, 0, stream>>>(BM, C1, c4w, c4b, FT);
    k_gnstats<<<dim3(64,16), 256, 0, stream>>>(FT, 4*NN, st4);
    k_gnapply<<<(64*NN+255)/256, 256, 0, stream>>>(FT, g4s, g4b, st4, NN, 4, 64*NN);

    // gather + MLP head: 2P items, one wave each
    k_mlp<<<(2*PP)/4, 256, 0, stream>>>(pose, X, pairs, FT,
                                        gw, gb, hw_, hb, ow, ob, (float*)d_out);
}

// Round 3
// 697.972 us; speedup vs baseline: 16.3625x; 1.8743x over previous
//
#include <hip/hip_runtime.h>
#include <math.h>

#define HH 480
#define WW 600
#define NN (HH*WW)      // 288000
#define PP 2048
#define H2 240
#define W2 300
#define N2 (H2*W2)      // 72000

typedef __bf16 bf16x8 __attribute__((ext_vector_type(8)));
typedef float  f32x4  __attribute__((ext_vector_type(4)));

__device__ __forceinline__ ushort f2b(float f) {
    unsigned u = __float_as_uint(f);
    unsigned r = (u + 0x7FFF + ((u >> 16) & 1)) >> 16;
    return (ushort)r;
}
__device__ __forceinline__ float b2f(ushort u) {
    return __uint_as_float(((unsigned)u) << 16);
}

// ---- workspace layout (bytes) ----
constexpr size_t alup(size_t x) { return (x + 4095) & ~(size_t)4095; }
constexpr size_t OFF_X   = 4096;
constexpr size_t OFF_C1B = alup(OFF_X   + 3UL*NN*4);
constexpr size_t OFF_D1R = alup(OFF_C1B + 32UL*NN*2);   // fp32 raw, also BM raw (aliased)
constexpr size_t OFF_D1B = alup(OFF_D1R + 64UL*N2*4);
constexpr size_t OFF_BMB = alup(OFF_D1B + 64UL*N2*2);
constexpr size_t OFF_WB3 = alup(OFF_BMB + 64UL*N2*2);
constexpr size_t OFF_WB4 = alup(OFF_WB3 + 36864UL*2);
constexpr size_t OFF_FT  = alup(OFF_WB4 + 55296UL*2);   // fp32; front also holds C1 raw

// ---------------- depth mean ----------------
__global__ void k_sum(const float* __restrict__ d, float* __restrict__ ws) {
    float s = 0.f;
    for (int i = blockIdx.x*blockDim.x + threadIdx.x; i < NN; i += gridDim.x*blockDim.x)
        s += d[i];
    #pragma unroll
    for (int o = 32; o; o >>= 1) s += __shfl_down(s, o, 64);
    __shared__ float sm[4];
    int wid = threadIdx.x >> 6;
    if ((threadIdx.x & 63) == 0) sm[wid] = s;
    __syncthreads();
    if (threadIdx.x == 0) {
        float t = 0.f;
        for (int w = 0; w < (int)(blockDim.x >> 6); ++w) t += sm[w];
        atomicAdd(ws, t);
    }
}

__global__ void k_buildx(const float* __restrict__ depth, const float* __restrict__ mask,
                         const float* __restrict__ ws, float* __restrict__ x) {
    int i = blockIdx.x*blockDim.x + threadIdx.x;
    if (i >= NN) return;
    float mean = ws[0] * (1.0f/NN);
    x[i]        = (depth[i] - mean) * 10.0f;
    x[NN + i]   = mask[i];
    x[2*NN + i] = 0.f;
}

__global__ void k_scatter(const int* __restrict__ pairs, float* __restrict__ x) {
    int p = blockIdx.x*blockDim.x + threadIdx.x;
    if (p < PP) x[2*NN + pairs[2*p]] = 1.0f;
}

// ------------- weight pre-transform to MFMA A-fragment layout (bf16) -------------
// dst[((t*NCH + c)*64 + co)*32 + k] = w[co][c*32+k][t]   (t = ky*3+kx)
__global__ void k_wcvt(const float* __restrict__ w, ushort* __restrict__ dst, int NCH) {
    int e = blockIdx.x*256 + threadIdx.x;
    int total = 9*NCH*64*32;
    if (e >= total) return;
    int k  = e & 31;
    int co = (e >> 5) & 63;
    int rest = e >> 11;          // t*NCH + c
    int c = rest % NCH;
    int t = rest / NCH;
    dst[e] = f2b(w[(co*(NCH*32) + c*32 + k)*9 + t]);
}

// ---------------- direct 3x3 conv, fp32 input (conv1) ----------------
template<int CIN, int STRIDE, int PT, int TCO>
__global__ __launch_bounds__(64) void k_conv_t(const float* __restrict__ in,
        const float* __restrict__ w, const float* __restrict__ bias,
        float* __restrict__ out, int Hi, int Wi, int Ho, int Wo) {
    int x   = blockIdx.x*64 + threadIdx.x;
    int y   = blockIdx.y;
    int co0 = blockIdx.z*TCO;
    if (x >= Wo) return;
    float acc[TCO];
    #pragma unroll
    for (int c = 0; c < TCO; ++c) acc[c] = bias[co0+c];
    int  xb   = x*STRIDE - PT;
    bool xint = (xb >= 0) && (xb + 2 < Wi);
    for (int ci = 0; ci < CIN; ++ci) {
        const float* ip = in + (long)ci*Hi*Wi;
        float iv[3][3];
        #pragma unroll
        for (int dy = 0; dy < 3; ++dy) {
            int iy = y*STRIDE + dy - PT;
            if ((unsigned)iy < (unsigned)Hi) {
                const float* rp = ip + (long)iy*Wi + xb;
                if (xint) { iv[dy][0]=rp[0]; iv[dy][1]=rp[1]; iv[dy][2]=rp[2]; }
                else {
                    #pragma unroll
                    for (int dx = 0; dx < 3; ++dx) {
                        int ix = xb + dx;
                        iv[dy][dx] = ((unsigned)ix < (unsigned)Wi) ? ip[(long)iy*Wi+ix] : 0.f;
                    }
                }
            } else iv[dy][0]=iv[dy][1]=iv[dy][2]=0.f;
        }
        const float* wp = w + ((long)co0*CIN + ci)*9;
        #pragma unroll
        for (int c = 0; c < TCO; ++c)
            #pragma unroll
            for (int k = 0; k < 9; ++k)
                acc[c] += iv[k/3][k%3] * wp[(long)c*CIN*9 + k];
    }
    #pragma unroll
    for (int c = 0; c < TCO; ++c)
        out[((long)(co0+c)*Ho + y)*Wo + x] = acc[c];
}

// ---------------- direct 3x3 conv, bf16 input (conv2, stride 2) ----------------
template<int CIN, int STRIDE, int PT, int TCO>
__global__ __launch_bounds__(64) void k_conv_b(const ushort* __restrict__ in,
        const float* __restrict__ w, const float* __restrict__ bias,
        float* __restrict__ out, int Hi, int Wi, int Ho, int Wo) {
    int x   = blockIdx.x*64 + threadIdx.x;
    int y   = blockIdx.y;
    int co0 = blockIdx.z*TCO;
    if (x >= Wo) return;
    float acc[TCO];
    #pragma unroll
    for (int c = 0; c < TCO; ++c) acc[c] = bias[co0+c];
    int  xb   = x*STRIDE - PT;
    bool xint = (xb >= 0) && (xb + 2 < Wi);
    for (int ci = 0; ci < CIN; ++ci) {
        const ushort* ip = in + (long)ci*Hi*Wi;
        float iv[3][3];
        #pragma unroll
        for (int dy = 0; dy < 3; ++dy) {
            int iy = y*STRIDE + dy - PT;
            if ((unsigned)iy < (unsigned)Hi) {
                const ushort* rp = ip + (long)iy*Wi + xb;
                if (xint) { iv[dy][0]=b2f(rp[0]); iv[dy][1]=b2f(rp[1]); iv[dy][2]=b2f(rp[2]); }
                else {
                    #pragma unroll
                    for (int dx = 0; dx < 3; ++dx) {
                        int ix = xb + dx;
                        iv[dy][dx] = ((unsigned)ix < (unsigned)Wi) ? b2f(ip[(long)iy*Wi+ix]) : 0.f;
                    }
                }
            } else iv[dy][0]=iv[dy][1]=iv[dy][2]=0.f;
        }
        const float* wp = w + ((long)co0*CIN + ci)*9;
        #pragma unroll
        for (int c = 0; c < TCO; ++c)
            #pragma unroll
            for (int k = 0; k < 9; ++k)
                acc[c] += iv[k/3][k%3] * wp[(long)c*CIN*9 + k];
    }
    #pragma unroll
    for (int c = 0; c < TCO; ++c)
        out[((long)(co0+c)*Ho + y)*Wo + x] = acc[c];
}

// ---------------- MFMA implicit-GEMM 3x3 conv (conv3 / conv4) ----------------
// Block: 256 thr = 4 waves. Output tile: 4 rows x 48 px x 64 co (wave = 1 row).
// LDS: sh[6 rows][50 px][CINP ci] bf16.
// conv4 (C4=true): input = concat( upsample2x(BMb 64ch 240x300), C1b 32ch 480x600 ).
template<bool C4, int CIN, int NCH, int CINP>
__global__ __launch_bounds__(256) void k_cmfma(const ushort* __restrict__ inA,
        const ushort* __restrict__ inB, const ushort* __restrict__ wb,
        const float* __restrict__ bias, float* __restrict__ out) {
    constexpr int Hc = C4 ? HH : H2;   // conv space
    constexpr int Wc = C4 ? WW : W2;
    __shared__ ushort sh[6*50*CINP];

    int y0  = blockIdx.y * 4;
    int x0  = blockIdx.x * 48;
    int iy0 = y0 - 1;
    int ix0 = x0 - 1;

    // ---- stage input tile: sh[r][px][ci] ----
    for (int r = 0; r < 6; ++r) {
        int iy = iy0 + r;
        bool rv = (unsigned)iy < (unsigned)Hc;
        int iyh = iy >> 1;
        for (int e = threadIdx.x; e < 50*CIN; e += 256) {
            int ci = e / 50;
            int px = e - ci*50;
            int ix = ix0 + px;
            ushort v = 0;
            if (rv && (unsigned)ix < (unsigned)Wc) {
                if (C4) {
                    v = (ci < 64) ? inA[ci*N2 + iyh*W2 + (ix >> 1)]
                                  : inB[(ci-64)*NN + iy*WW + ix];
                } else {
                    v = inA[ci*N2 + iy*W2 + ix];
                }
            }
            sh[(r*50 + px)*CINP + ci] = v;
        }
    }
    __syncthreads();

    // ---- compute: 9 taps x NCH k-chunks, 4 co-tiles x 3 px-tiles per wave ----
    int w    = threadIdx.x >> 6;
    int lane = threadIdx.x & 63;
    int lm   = lane & 15;
    int lg   = lane >> 4;
    int y    = y0 + w;

    f32x4 acc[4][3];
    #pragma unroll
    for (int ct = 0; ct < 4; ++ct)
        #pragma unroll
        for (int pt = 0; pt < 3; ++pt) acc[ct][pt] = 0.f;

    for (int t = 0; t < 9; ++t) {
        int dy = t / 3, dx = t - dy*3;
        for (int c = 0; c < NCH; ++c) {
            bf16x8 a[4];
            const ushort* wp = wb + ((t*NCH + c)*64)*32;
            #pragma unroll
            for (int ct = 0; ct < 4; ++ct)
                a[ct] = *(const bf16x8*)(wp + (ct*16 + lm)*32 + lg*8);
            int r = w + dy;
            #pragma unroll
            for (int pt = 0; pt < 3; ++pt) {
                int px = pt*16 + lm + dx;
                bf16x8 b = *(const bf16x8*)(&sh[(r*50 + px)*CINP + c*32 + lg*8]);
                #pragma unroll
                for (int ct = 0; ct < 4; ++ct)
                    acc[ct][pt] = __builtin_amdgcn_mfma_f32_16x16x32_bf16(a[ct], b, acc[ct][pt], 0, 0, 0);
            }
        }
    }

    // ---- epilogue: C/D layout col(px)=lane&15, row(co)=(lane>>4)*4+reg ----
    #pragma unroll
    for (int ct = 0; ct < 4; ++ct) {
        #pragma unroll
        for (int pt = 0; pt < 3; ++pt) {
            int pxg = x0 + pt*16 + lm;
            if (pxg < Wc) {
                #pragma unroll
                for (int reg = 0; reg < 4; ++reg) {
                    int co = ct*16 + lg*4 + reg;
                    out[((long)co*Hc + y)*Wc + pxg] = acc[ct][pt][reg] + bias[co];
                }
            }
        }
    }
}

// ---------------- group norm stats ----------------
__global__ void k_gnstats(const float* __restrict__ x, int elems_per_group,
                          float* __restrict__ stat) {
    int g = blockIdx.y;
    const float* p = x + (long)g*elems_per_group;
    float s = 0.f, s2 = 0.f;
    for (int i = blockIdx.x*blockDim.x + threadIdx.x; i < elems_per_group; i += gridDim.x*blockDim.x) {
        float v = p[i]; s += v; s2 += v*v;
    }
    #pragma unroll
    for (int o = 32; o; o >>= 1) { s += __shfl_down(s,o,64); s2 += __shfl_down(s2,o,64); }
    __shared__ float sm[4], sm2[4];
    int wid = threadIdx.x >> 6;
    if ((threadIdx.x & 63) == 0) { sm[wid]=s; sm2[wid]=s2; }
    __syncthreads();
    if (threadIdx.x == 0) {
        float t=0.f, t2=0.f;
        for (int i = 0; i < (int)(blockDim.x >> 6); ++i) { t += sm[i]; t2 += sm2[i]; }
        atomicAdd(&stat[g], t);
        atomicAdd(&stat[16+g], t2);
    }
}

// ---------------- GN apply + lrelu, fp32 -> fp32 (in-place ok) ----------------
__global__ void k_gnapply(float* __restrict__ x, const float* __restrict__ scale,
                          const float* __restrict__ bias, const float* __restrict__ stat,
                          int HW, int chper, int total) {
    int i = blockIdx.x*blockDim.x + threadIdx.x;
    if (i >= total) return;
    int c = i / HW;
    int g = c / chper;
    float cnt = (float)chper * (float)HW;
    float mu  = stat[g] / cnt;
    float var = stat[16+g] / cnt - mu*mu;
    float rs  = rsqrtf(var + 1e-5f);
    float v = (x[i] - mu) * rs * scale[c] + bias[c];
    x[i] = v >= 0.f ? v : 0.2f*v;
}

// ---------------- GN apply + lrelu, fp32 -> bf16 ----------------
__global__ void k_gnapply_b(const float* __restrict__ x, ushort* __restrict__ y,
                            const float* __restrict__ scale, const float* __restrict__ bias,
                            const float* __restrict__ stat,
                            int HW, int chper, int total) {
    int i = blockIdx.x*blockDim.x + threadIdx.x;
    if (i >= total) return;
    int c = i / HW;
    int g = c / chper;
    float cnt = (float)chper * (float)HW;
    float mu  = stat[g] / cnt;
    float var = stat[16+g] / cnt - mu*mu;
    float rs  = rsqrtf(var + 1e-5f);
    float v = (x[i] - mu) * rs * scale[c] + bias[c];
    y[i] = f2b(v >= 0.f ? v : 0.2f*v);
}

// ---------------- gather + MLP head ----------------
__global__ void k_mlp(const float* __restrict__ pose, const float* __restrict__ sd,
                      const int* __restrict__ pairs, const float* __restrict__ feats,
                      const float* __restrict__ gw, const float* __restrict__ gb,
                      const float* __restrict__ hw, const float* __restrict__ hb,
                      const float* __restrict__ ow, const float* __restrict__ ob,
                      float* __restrict__ out) {
    int wid  = threadIdx.x >> 6;
    int lane = threadIdx.x & 63;
    int t = blockIdx.x*4 + wid;
    int p = t >> 1;
    const float* pp = pose + t*8;
    float q0=pp[0], q1=pp[1], q2=pp[2], q3=pp[3];
    float f0=pp[4], f1=pp[5], f2=pp[6], tr=pp[7];
    int idx = pairs[2*p];
    float dg = sd[idx];
    float cond[15] = {q0*q0,q0*q1,q0*q2,q0*q3,q1*q1,q1*q2,q1*q3,q2*q2,q2*q3,q3*q3,
                      f0,f1,f2,tr,dg};
    float acc = gb[lane];
    #pragma unroll
    for (int k = 0; k < 15; ++k) acc += cond[k]*gw[k*64+lane];
    float gate = 1.f/(1.f+expf(-acc));
    float fg = feats[(long)lane*NN + idx];
    float h = fg*gate;
    float ss = h*h;
    #pragma unroll
    for (int o = 32; o; o >>= 1) ss += __shfl_xor(ss, o, 64);
    h *= rsqrtf(ss + 1e-8f);
    __shared__ float hs[4][64];
    hs[wid][lane] = h;
    __syncthreads();
    float a2 = hb[lane];
    #pragma unroll 8
    for (int d = 0; d < 64; ++d) a2 += hs[wid][d]*hw[d*64+lane];
    float h2 = a2 >= 0.f ? a2 : 0.2f*a2;
    float si = h2 / (1.f+expf(-h2));
    float v = si * ow[lane];
    #pragma unroll
    for (int o = 32; o; o >>= 1) v += __shfl_xor(v, o, 64);
    if (lane == 0) out[t] = v + ob[0];
}

extern "C" void kernel_launch(void* const* d_in, const int* in_sizes, int n_in,
                              void* d_out, int out_size, void* d_ws, size_t ws_size,
                              hipStream_t stream) {
    const float* depth = (const float*)d_in[0];
    const float* pose  = (const float*)d_in[1];
    const float* mask  = (const float*)d_in[2];
    const int*   pairs = (const int*)  d_in[3];
    const float* c1w = (const float*)d_in[4];  const float* c1b = (const float*)d_in[5];
    const float* g1s = (const float*)d_in[6];  const float* g1b = (const float*)d_in[7];
    const float* c2w = (const float*)d_in[8];  const float* c2b = (const float*)d_in[9];
    const float* g2s = (const float*)d_in[10]; const float* g2b = (const float*)d_in[11];
    const float* c3w = (const float*)d_in[12]; const float* c3b = (const float*)d_in[13];
    const float* g3s = (const float*)d_in[14]; const float* g3b = (const float*)d_in[15];
    const float* c4w = (const float*)d_in[16]; const float* c4b = (const float*)d_in[17];
    const float* g4s = (const float*)d_in[18]; const float* g4b = (const float*)d_in[19];
    const float* gw  = (const float*)d_in[20]; const float* gb  = (const float*)d_in[21];
    const float* hw_ = (const float*)d_in[22]; const float* hb  = (const float*)d_in[23];
    const float* ow  = (const float*)d_in[24]; const float* ob  = (const float*)d_in[25];

    char* base = (char*)d_ws;
    float*  stats = (float*) base;
    float*  X   = (float*) (base + OFF_X);
    ushort* C1B = (ushort*)(base + OFF_C1B);
    float*  D1R = (float*) (base + OFF_D1R);   // conv2 raw; later conv3 raw (BM)
    ushort* D1B = (ushort*)(base + OFF_D1B);
    ushort* BMB = (ushort*)(base + OFF_BMB);
    ushort* WB3 = (ushort*)(base + OFF_WB3);
    ushort* WB4 = (ushort*)(base + OFF_WB4);
    float*  FT  = (float*) (base + OFF_FT);
    float*  C1R = FT;                           // alias: C1 raw lives in FT region early
    float* st1 = stats + 16;
    float* st2 = stats + 64;
    float* st3 = stats + 112;
    float* st4 = stats + 160;

    hipMemsetAsync(d_ws, 0, 1024, stream);

    k_sum    <<<1024, 256, 0, stream>>>(depth, stats);
    k_buildx <<<(NN+255)/256, 256, 0, stream>>>(depth, mask, stats, X);
    k_scatter<<<(PP+255)/256, 256, 0, stream>>>(pairs, X);
    k_wcvt   <<<144, 256, 0, stream>>>(c3w, WB3, 2);
    k_wcvt   <<<216, 256, 0, stream>>>(c4w, WB4, 3);

    // conv1: 3->32 fp32, 480x600  -> C1R (raw)
    k_conv_t<3,1,1,16><<<dim3(10, HH, 2), 64, 0, stream>>>(X, c1w, c1b, C1R, HH, WW, HH, WW);
    k_gnstats  <<<dim3(64,16), 256, 0, stream>>>(C1R, 2*NN, st1);
    k_gnapply_b<<<(32*NN+255)/256, 256, 0, stream>>>(C1R, C1B, g1s, g1b, st1, NN, 2, 32*NN);

    // conv2: 32->64 stride2, bf16 in -> D1R (raw fp32)
    k_conv_b<32,2,0,16><<<dim3(5, H2, 4), 64, 0, stream>>>(C1B, c2w, c2b, D1R, HH, WW, H2, W2);
    k_gnstats  <<<dim3(64,16), 256, 0, stream>>>(D1R, 4*N2, st2);
    k_gnapply_b<<<(64*N2+255)/256, 256, 0, stream>>>(D1R, D1B, g2s, g2b, st2, N2, 4, 64*N2);

    // conv3: 64->64 MFMA, 240x300 -> D1R region (BM raw)
    k_cmfma<false,64,2,72><<<dim3(7, 60), 256, 0, stream>>>(D1B, nullptr, WB3, c3b, D1R);
    k_gnstats  <<<dim3(64,16), 256, 0, stream>>>(D1R, 4*N2, st3);
    k_gnapply_b<<<(64*N2+255)/256, 256, 0, stream>>>(D1R, BMB, g3s, g3b, st3, N2, 4, 64*N2);

    // conv4: concat(up(BM), C1) 96->64 MFMA, 480x600 -> FT
    k_cmfma<true,96,3,104><<<dim3(13, 120), 256, 0, stream>>>(BMB, C1B, WB4, c4b, FT);
    k_gnstats <<<dim3(64,16), 256, 0, stream>>>(FT, 4*NN, st4);
    k_gnapply <<<(64*NN+255)/256, 256, 0, stream>>>(FT, g4s, g4b, st4, NN, 4, 64*NN);

    // gather + MLP head
    k_mlp<<<(2*PP)/4, 256, 0, stream>>>(pose, X, pairs, FT,
                                        gw, gb, hw_, hb, ow, ob, (float*)d_out);
}

// Round 4
// 479.835 us; speedup vs baseline: 23.8010x; 1.4546x over previous
//
#include <hip/hip_runtime.h>
#include <math.h>

#define HH 480
#define WW 600
#define NN (HH*WW)      // 288000
#define PP 2048
#define H2 240
#define W2 300
#define N2 (H2*W2)      // 72000

typedef __bf16  bf16x8  __attribute__((ext_vector_type(8)));
typedef float   f32x4   __attribute__((ext_vector_type(4)));
typedef ushort  ushort8 __attribute__((ext_vector_type(8)));

__device__ __forceinline__ ushort f2b(float f) {
    unsigned u = __float_as_uint(f);
    unsigned r = (u + 0x7FFF + ((u >> 16) & 1)) >> 16;
    return (ushort)r;
}
__device__ __forceinline__ float b2f(ushort u) {
    return __uint_as_float(((unsigned)u) << 16);
}

// ---- workspace layout (bytes) ----
constexpr size_t alup(size_t x) { return (x + 4095) & ~(size_t)4095; }
constexpr size_t OFF_X   = 4096;
constexpr size_t OFF_C1B = alup(OFF_X   + 3UL*NN*4);
constexpr size_t OFF_D1R = alup(OFF_C1B + 32UL*NN*2);   // fp32 raw conv2; later conv3 raw (BM)
constexpr size_t OFF_D1B = alup(OFF_D1R + 64UL*N2*4);
constexpr size_t OFF_BMB = alup(OFF_D1B + 64UL*N2*2);
constexpr size_t OFF_WB3 = alup(OFF_BMB + 64UL*N2*2);
constexpr size_t OFF_WB4 = alup(OFF_WB3 + 36864UL*2);
constexpr size_t OFF_FT  = alup(OFF_WB4 + 55296UL*2);   // fp32; front also holds C1 raw

// ---------------- depth mean ----------------
__global__ void k_sum(const float* __restrict__ d, float* __restrict__ ws) {
    float s = 0.f;
    for (int i = blockIdx.x*blockDim.x + threadIdx.x; i < NN; i += gridDim.x*blockDim.x)
        s += d[i];
    #pragma unroll
    for (int o = 32; o; o >>= 1) s += __shfl_down(s, o, 64);
    __shared__ float sm[4];
    int wid = threadIdx.x >> 6;
    if ((threadIdx.x & 63) == 0) sm[wid] = s;
    __syncthreads();
    if (threadIdx.x == 0) {
        float t = 0.f;
        for (int w = 0; w < (int)(blockDim.x >> 6); ++w) t += sm[w];
        atomicAdd(ws, t);
    }
}

__global__ void k_buildx(const float* __restrict__ depth, const float* __restrict__ mask,
                         const float* __restrict__ ws, float* __restrict__ x) {
    int i = blockIdx.x*blockDim.x + threadIdx.x;
    if (i >= NN) return;
    float mean = ws[0] * (1.0f/NN);
    x[i]        = (depth[i] - mean) * 10.0f;
    x[NN + i]   = mask[i];
    x[2*NN + i] = 0.f;
}

__global__ void k_scatter(const int* __restrict__ pairs, float* __restrict__ x) {
    int p = blockIdx.x*blockDim.x + threadIdx.x;
    if (p < PP) x[2*NN + pairs[2*p]] = 1.0f;
}

// ------------- weight pre-transform to MFMA A-fragment layout (bf16) -------------
// dst[((t*NCH + c)*64 + co)*32 + k] = w[co][c*32+k][t]   (t = ky*3+kx)
__global__ void k_wcvt(const float* __restrict__ w, ushort* __restrict__ dst, int NCH) {
    int e = blockIdx.x*256 + threadIdx.x;
    int total = 9*NCH*64*32;
    if (e >= total) return;
    int k  = e & 31;
    int co = (e >> 5) & 63;
    int rest = e >> 11;          // t*NCH + c
    int c = rest % NCH;
    int t = rest / NCH;
    dst[e] = f2b(w[(co*(NCH*32) + c*32 + k)*9 + t]);
}

// ---------------- direct 3x3 conv, fp32 input (conv1) ----------------
template<int CIN, int STRIDE, int PT, int TCO>
__global__ __launch_bounds__(64) void k_conv_t(const float* __restrict__ in,
        const float* __restrict__ w, const float* __restrict__ bias,
        float* __restrict__ out, int Hi, int Wi, int Ho, int Wo) {
    int x   = blockIdx.x*64 + threadIdx.x;
    int y   = blockIdx.y;
    int co0 = blockIdx.z*TCO;
    if (x >= Wo) return;
    float acc[TCO];
    #pragma unroll
    for (int c = 0; c < TCO; ++c) acc[c] = bias[co0+c];
    int  xb   = x*STRIDE - PT;
    bool xint = (xb >= 0) && (xb + 2 < Wi);
    for (int ci = 0; ci < CIN; ++ci) {
        const float* ip = in + (long)ci*Hi*Wi;
        float iv[3][3];
        #pragma unroll
        for (int dy = 0; dy < 3; ++dy) {
            int iy = y*STRIDE + dy - PT;
            if ((unsigned)iy < (unsigned)Hi) {
                const float* rp = ip + (long)iy*Wi + xb;
                if (xint) { iv[dy][0]=rp[0]; iv[dy][1]=rp[1]; iv[dy][2]=rp[2]; }
                else {
                    #pragma unroll
                    for (int dx = 0; dx < 3; ++dx) {
                        int ix = xb + dx;
                        iv[dy][dx] = ((unsigned)ix < (unsigned)Wi) ? ip[(long)iy*Wi+ix] : 0.f;
                    }
                }
            } else iv[dy][0]=iv[dy][1]=iv[dy][2]=0.f;
        }
        const float* wp = w + ((long)co0*CIN + ci)*9;
        #pragma unroll
        for (int c = 0; c < TCO; ++c)
            #pragma unroll
            for (int k = 0; k < 9; ++k)
                acc[c] += iv[k/3][k%3] * wp[(long)c*CIN*9 + k];
    }
    #pragma unroll
    for (int c = 0; c < TCO; ++c)
        out[((long)(co0+c)*Ho + y)*Wo + x] = acc[c];
}

// ---------------- direct 3x3 conv, bf16 input (conv2, stride 2) ----------------
template<int CIN, int STRIDE, int PT, int TCO>
__global__ __launch_bounds__(64) void k_conv_b(const ushort* __restrict__ in,
        const float* __restrict__ w, const float* __restrict__ bias,
        float* __restrict__ out, int Hi, int Wi, int Ho, int Wo) {
    int x   = blockIdx.x*64 + threadIdx.x;
    int y   = blockIdx.y;
    int co0 = blockIdx.z*TCO;
    if (x >= Wo) return;
    float acc[TCO];
    #pragma unroll
    for (int c = 0; c < TCO; ++c) acc[c] = bias[co0+c];
    int  xb   = x*STRIDE - PT;
    bool xint = (xb >= 0) && (xb + 2 < Wi);
    for (int ci = 0; ci < CIN; ++ci) {
        const ushort* ip = in + (long)ci*Hi*Wi;
        float iv[3][3];
        #pragma unroll
        for (int dy = 0; dy < 3; ++dy) {
            int iy = y*STRIDE + dy - PT;
            if ((unsigned)iy < (unsigned)Hi) {
                const ushort* rp = ip + (long)iy*Wi + xb;
                if (xint) { iv[dy][0]=b2f(rp[0]); iv[dy][1]=b2f(rp[1]); iv[dy][2]=b2f(rp[2]); }
                else {
                    #pragma unroll
                    for (int dx = 0; dx < 3; ++dx) {
                        int ix = xb + dx;
                        iv[dy][dx] = ((unsigned)ix < (unsigned)Wi) ? b2f(ip[(long)iy*Wi+ix]) : 0.f;
                    }
                }
            } else iv[dy][0]=iv[dy][1]=iv[dy][2]=0.f;
        }
        const float* wp = w + ((long)co0*CIN + ci)*9;
        #pragma unroll
        for (int c = 0; c < TCO; ++c)
            #pragma unroll
            for (int k = 0; k < 9; ++k)
                acc[c] += iv[k/3][k%3] * wp[(long)c*CIN*9 + k];
    }
    #pragma unroll
    for (int c = 0; c < TCO; ++c)
        out[((long)(co0+c)*Ho + y)*Wo + x] = acc[c];
}

// ---------------- MFMA implicit-GEMM 3x3 conv (conv3 / conv4) ----------------
// Block: 256 thr = 4 waves; output tile 4 rows x 64 px x 64 co (wave = 1 row).
// K chunked by 32 ci; LDS sh[6 rows][66 px][40 ci-pad] per chunk (31.7 KB).
// Staging: lane=px, 8 coalesced 2B global loads -> one ds_write_b128
// (stride 80 B = 20-bank inc -> full 32-bank coverage, conflict-free).
// GN stats (sum/sumsq per group) fused into epilogue.
template<bool C4, int NCH>
__global__ __launch_bounds__(256) void k_cmfma(const ushort* __restrict__ inA,
        const ushort* __restrict__ inB, const ushort* __restrict__ wb,
        const float* __restrict__ bias, float* __restrict__ out,
        float* __restrict__ stat) {
    constexpr int Hc  = C4 ? HH : H2;
    constexpr int Wc  = C4 ? WW : W2;
    constexpr int PXS = 66;
    constexpr int CP  = 40;
    __shared__ __align__(16) ushort sh[6*PXS*CP];
    __shared__ float sred[4][16][2];

    int y0 = blockIdx.y*4;
    int x0 = blockIdx.x*64;
    int w    = threadIdx.x >> 6;
    int lane = threadIdx.x & 63;
    int lm   = lane & 15;
    int lg   = lane >> 4;

    f32x4 acc[4][4];
    #pragma unroll
    for (int ct = 0; ct < 4; ++ct)
        #pragma unroll
        for (int pt = 0; pt < 4; ++pt) acc[ct][pt] = 0.f;

    for (int kc = 0; kc < NCH; ++kc) {
        if (kc) __syncthreads();
        // ---- stage chunk kc: 24 task-groups (6 rows x 4 ci-octets) over 4 waves
        for (int i = 0; i < 6; ++i) {
            int gid = i*4 + w;
            int r   = gid >> 2;
            int cg  = gid & 3;
            int iy  = y0 - 1 + r;
            int ci0 = kc*32 + cg*8;
            #pragma unroll
            for (int half = 0; half < 2; ++half) {
                int px = half ? 64 + lane : lane;
                if (half && lane >= 2) continue;
                int ix = x0 - 1 + px;
                ushort v[8] = {0,0,0,0,0,0,0,0};
                if ((unsigned)iy < (unsigned)Hc && (unsigned)ix < (unsigned)Wc) {
                    if (!C4) {
                        const ushort* p = inA + (size_t)ci0*N2 + (size_t)iy*W2 + ix;
                        #pragma unroll
                        for (int j = 0; j < 8; ++j) v[j] = p[(size_t)j*N2];
                    } else if (ci0 < 64) {
                        const ushort* p = inA + (size_t)ci0*N2 + (size_t)(iy>>1)*W2 + (ix>>1);
                        #pragma unroll
                        for (int j = 0; j < 8; ++j) v[j] = p[(size_t)j*N2];
                    } else {
                        const ushort* p = inB + (size_t)(ci0-64)*NN + (size_t)iy*WW + ix;
                        #pragma unroll
                        for (int j = 0; j < 8; ++j) v[j] = p[(size_t)j*NN];
                    }
                }
                ushort8 pk;
                #pragma unroll
                for (int j = 0; j < 8; ++j) pk[j] = v[j];
                *(ushort8*)&sh[(r*PXS + px)*CP + cg*8] = pk;
            }
        }
        __syncthreads();
        // ---- compute chunk kc: 9 taps x 4 px-tiles x 4 co-tiles
        #pragma unroll
        for (int t = 0; t < 9; ++t) {
            const int dy = t/3, dx = t - 3*(t/3);
            const ushort* wp = wb + ((size_t)(t*NCH + kc)*64)*32;
            bf16x8 a[4];
            #pragma unroll
            for (int ct = 0; ct < 4; ++ct)
                a[ct] = *(const bf16x8*)(wp + (ct*16 + lm)*32 + lg*8);
            int rbase = (w + dy)*PXS;
            #pragma unroll
            for (int pt = 0; pt < 4; ++pt) {
                bf16x8 b = *(const bf16x8*)&sh[(rbase + pt*16 + lm + dx)*CP + lg*8];
                #pragma unroll
                for (int ct = 0; ct < 4; ++ct)
                    acc[ct][pt] = __builtin_amdgcn_mfma_f32_16x16x32_bf16(a[ct], b, acc[ct][pt], 0, 0, 0);
            }
        }
    }

    // ---- epilogue: bias + store + fused GN stats (chper=4: group = co>>2 = ct*4+lg)
    int y = y0 + w;
    #pragma unroll
    for (int ct = 0; ct < 4; ++ct) {
        float s = 0.f, s2 = 0.f;
        #pragma unroll
        for (int pt = 0; pt < 4; ++pt) {
            int pxg = x0 + pt*16 + lm;
            bool vld = pxg < Wc;
            #pragma unroll
            for (int reg = 0; reg < 4; ++reg) {
                int co = ct*16 + lg*4 + reg;
                float v = acc[ct][pt][reg] + bias[co];
                if (vld) {
                    out[((size_t)co*Hc + y)*Wc + pxg] = v;
                    s += v; s2 += v*v;
                }
            }
        }
        #pragma unroll
        for (int o = 1; o < 16; o <<= 1) {
            s  += __shfl_xor(s,  o, 64);
            s2 += __shfl_xor(s2, o, 64);
        }
        if (lm == 0) { sred[w][ct*4+lg][0] = s; sred[w][ct*4+lg][1] = s2; }
    }
    __syncthreads();
    if (threadIdx.x < 32) {
        int g = threadIdx.x >> 1, k = threadIdx.x & 1;
        float t = sred[0][g][k] + sred[1][g][k] + sred[2][g][k] + sred[3][g][k];
        atomicAdd(&stat[k*16 + g], t);
    }
}

// ---------------- group norm stats (layers 1,2) ----------------
__global__ void k_gnstats(const float* __restrict__ x, int elems_per_group,
                          float* __restrict__ stat) {
    int g = blockIdx.y;
    const float* p = x + (long)g*elems_per_group;
    float s = 0.f, s2 = 0.f;
    for (int i = blockIdx.x*blockDim.x + threadIdx.x; i < elems_per_group; i += gridDim.x*blockDim.x) {
        float v = p[i]; s += v; s2 += v*v;
    }
    #pragma unroll
    for (int o = 32; o; o >>= 1) { s += __shfl_down(s,o,64); s2 += __shfl_down(s2,o,64); }
    __shared__ float sm[4], sm2[4];
    int wid = threadIdx.x >> 6;
    if ((threadIdx.x & 63) == 0) { sm[wid]=s; sm2[wid]=s2; }
    __syncthreads();
    if (threadIdx.x == 0) {
        float t=0.f, t2=0.f;
        for (int i = 0; i < (int)(blockDim.x >> 6); ++i) { t += sm[i]; t2 += sm2[i]; }
        atomicAdd(&stat[g], t);
        atomicAdd(&stat[16+g], t2);
    }
}

// ---------------- GN apply + lrelu, fp32 -> bf16 ----------------
__global__ void k_gnapply_b(const float* __restrict__ x, ushort* __restrict__ y,
                            const float* __restrict__ scale, const float* __restrict__ bias,
                            const float* __restrict__ stat,
                            int HW, int chper, int total) {
    int i = blockIdx.x*blockDim.x + threadIdx.x;
    if (i >= total) return;
    int c = i / HW;
    int g = c / chper;
    float cnt = (float)chper * (float)HW;
    float mu  = stat[g] / cnt;
    float var = stat[16+g] / cnt - mu*mu;
    float rs  = rsqrtf(var + 1e-5f);
    float v = (x[i] - mu) * rs * scale[c] + bias[c];
    y[i] = f2b(v >= 0.f ? v : 0.2f*v);
}

// ---------------- gather + GN(L4, fused) + MLP head ----------------
__global__ void k_mlp(const float* __restrict__ pose, const float* __restrict__ sd,
                      const int* __restrict__ pairs, const float* __restrict__ feats,
                      const float* __restrict__ g4s, const float* __restrict__ g4b,
                      const float* __restrict__ st4,
                      const float* __restrict__ gw, const float* __restrict__ gb,
                      const float* __restrict__ hw, const float* __restrict__ hb,
                      const float* __restrict__ ow, const float* __restrict__ ob,
                      float* __restrict__ out) {
    int wid  = threadIdx.x >> 6;
    int lane = threadIdx.x & 63;
    int t = blockIdx.x*4 + wid;
    int p = t >> 1;
    const float* pp = pose + t*8;
    float q0=pp[0], q1=pp[1], q2=pp[2], q3=pp[3];
    float f0=pp[4], f1=pp[5], f2=pp[6], tr=pp[7];
    int idx = pairs[2*p];
    float dg = sd[idx];
    float cond[15] = {q0*q0,q0*q1,q0*q2,q0*q3,q1*q1,q1*q2,q1*q3,q2*q2,q2*q3,q3*q3,
                      f0,f1,f2,tr,dg};
    float acc = gb[lane];
    #pragma unroll
    for (int k = 0; k < 15; ++k) acc += cond[k]*gw[k*64+lane];
    float gate = 1.f/(1.f+expf(-acc));
    // gather raw conv4 output + apply GN(L4)+lrelu on the fly (channel=lane, group=lane>>2)
    float raw = feats[(size_t)lane*NN + idx];
    int   g4  = lane >> 2;
    float cnt = 4.0f * (float)NN;
    float mu  = st4[g4] / cnt;
    float var = st4[16+g4] / cnt - mu*mu;
    float rs  = rsqrtf(var + 1e-5f);
    float fv  = (raw - mu) * rs * g4s[lane] + g4b[lane];
    float fg  = fv >= 0.f ? fv : 0.2f*fv;
    float h = fg*gate;
    float ss = h*h;
    #pragma unroll
    for (int o = 32; o; o >>= 1) ss += __shfl_xor(ss, o, 64);
    h *= rsqrtf(ss + 1e-8f);
    __shared__ float hs[4][64];
    hs[wid][lane] = h;
    __syncthreads();
    float a2 = hb[lane];
    #pragma unroll 8
    for (int d = 0; d < 64; ++d) a2 += hs[wid][d]*hw[d*64+lane];
    float h2 = a2 >= 0.f ? a2 : 0.2f*a2;
    float si = h2 / (1.f+expf(-h2));
    float v = si * ow[lane];
    #pragma unroll
    for (int o = 32; o; o >>= 1) v += __shfl_xor(v, o, 64);
    if (lane == 0) out[t] = v + ob[0];
}

extern "C" void kernel_launch(void* const* d_in, const int* in_sizes, int n_in,
                              void* d_out, int out_size, void* d_ws, size_t ws_size,
                              hipStream_t stream) {
    const float* depth = (const float*)d_in[0];
    const float* pose  = (const float*)d_in[1];
    const float* mask  = (const float*)d_in[2];
    const int*   pairs = (const int*)  d_in[3];
    const float* c1w = (const float*)d_in[4];  const float* c1b = (const float*)d_in[5];
    const float* g1s = (const float*)d_in[6];  const float* g1b = (const float*)d_in[7];
    const float* c2w = (const float*)d_in[8];  const float* c2b = (const float*)d_in[9];
    const float* g2s = (const float*)d_in[10]; const float* g2b = (const float*)d_in[11];
    const float* c3w = (const float*)d_in[12]; const float* c3b = (const float*)d_in[13];
    const float* g3s = (const float*)d_in[14]; const float* g3b = (const float*)d_in[15];
    const float* c4w = (const float*)d_in[16]; const float* c4b = (const float*)d_in[17];
    const float* g4s = (const float*)d_in[18]; const float* g4b = (const float*)d_in[19];
    const float* gw  = (const float*)d_in[20]; const float* gb  = (const float*)d_in[21];
    const float* hw_ = (const float*)d_in[22]; const float* hb  = (const float*)d_in[23];
    const float* ow  = (const float*)d_in[24]; const float* ob  = (const float*)d_in[25];

    char* base = (char*)d_ws;
    float*  stats = (float*) base;
    float*  X   = (float*) (base + OFF_X);
    ushort* C1B = (ushort*)(base + OFF_C1B);
    float*  D1R = (float*) (base + OFF_D1R);
    ushort* D1B = (ushort*)(base + OFF_D1B);
    ushort* BMB = (ushort*)(base + OFF_BMB);
    ushort* WB3 = (ushort*)(base + OFF_WB3);
    ushort* WB4 = (ushort*)(base + OFF_WB4);
    float*  FT  = (float*) (base + OFF_FT);
    float*  C1R = FT;
    float* st1 = stats + 16;
    float* st2 = stats + 64;
    float* st3 = stats + 112;
    float* st4 = stats + 160;

    hipMemsetAsync(d_ws, 0, 1024, stream);

    k_sum    <<<1024, 256, 0, stream>>>(depth, stats);
    k_buildx <<<(NN+255)/256, 256, 0, stream>>>(depth, mask, stats, X);
    k_scatter<<<(PP+255)/256, 256, 0, stream>>>(pairs, X);
    k_wcvt   <<<144, 256, 0, stream>>>(c3w, WB3, 2);
    k_wcvt   <<<216, 256, 0, stream>>>(c4w, WB4, 3);

    // conv1: 3->32 fp32  -> C1R raw
    k_conv_t<3,1,1,16><<<dim3(10, HH, 2), 64, 0, stream>>>(X, c1w, c1b, C1R, HH, WW, HH, WW);
    k_gnstats  <<<dim3(64,16), 256, 0, stream>>>(C1R, 2*NN, st1);
    k_gnapply_b<<<(32*NN+255)/256, 256, 0, stream>>>(C1R, C1B, g1s, g1b, st1, NN, 2, 32*NN);

    // conv2: 32->64 stride2 -> D1R raw
    k_conv_b<32,2,0,16><<<dim3(5, H2, 4), 64, 0, stream>>>(C1B, c2w, c2b, D1R, HH, WW, H2, W2);
    k_gnstats  <<<dim3(64,16), 256, 0, stream>>>(D1R, 4*N2, st2);
    k_gnapply_b<<<(64*N2+255)/256, 256, 0, stream>>>(D1R, D1B, g2s, g2b, st2, N2, 4, 64*N2);

    // conv3: 64->64 MFMA (fused stats) -> D1R region (BM raw)
    k_cmfma<false,2><<<dim3(5, 60), 256, 0, stream>>>(D1B, nullptr, WB3, c3b, D1R, st3);
    k_gnapply_b<<<(64*N2+255)/256, 256, 0, stream>>>(D1R, BMB, g3s, g3b, st3, N2, 4, 64*N2);

    // conv4: concat(up(BM), C1) 96->64 MFMA (fused stats) -> FT raw
    k_cmfma<true,3><<<dim3(10, 120), 256, 0, stream>>>(BMB, C1B, WB4, c4b, FT, st4);

    // gather + GN(L4) + MLP head
    k_mlp<<<(2*PP)/4, 256, 0, stream>>>(pose, X, pairs, FT, g4s, g4b, st4,
                                        gw, gb, hw_, hb, ow, ob, (float*)d_out);
}

// Round 5
// 383.242 us; speedup vs baseline: 29.7999x; 1.2520x over previous
//
#include <hip/hip_runtime.h>
#include <math.h>

#define HH 480
#define WW 600
#define NN (HH*WW)      // 288000
#define PP 2048
#define H2 240
#define W2 300
#define N2 (H2*W2)      // 72000

typedef __bf16  bf16x8  __attribute__((ext_vector_type(8)));
typedef float   f32x4   __attribute__((ext_vector_type(4)));
typedef ushort  ushort8 __attribute__((ext_vector_type(8)));

__device__ __forceinline__ ushort f2b(float f) {
    unsigned u = __float_as_uint(f);
    unsigned r = (u + 0x7FFF + ((u >> 16) & 1)) >> 16;
    return (ushort)r;
}

__device__ __forceinline__ bf16x8 ld_bf8(const ushort* p, bool v) {
    ushort8 r = {};
    if (v) r = *(const ushort8*)p;
    return __builtin_bit_cast(bf16x8, r);
}

// ---- workspace layout (bytes) ----
constexpr size_t alup(size_t x) { return (x + 4095) & ~(size_t)4095; }
constexpr size_t OFF_X   = 4096;                         // 3*NN fp32 planar
constexpr size_t OFF_FT  = alup(OFF_X   + 3UL*NN*4);     // NN*64 fp32 [px][co]; front aliases C1R (NN*32 f32)
constexpr size_t OFF_C1P = alup(OFF_FT  + 64UL*NN*4);    // NN*32 bf16 [px][ci]
constexpr size_t OFF_D1R = alup(OFF_C1P + 32UL*NN*2);    // N2*64 fp32 [px][co] (conv2 raw, reused conv3 raw)
constexpr size_t OFF_D1P = alup(OFF_D1R + 64UL*N2*4);    // N2*64 bf16
constexpr size_t OFF_BMP = alup(OFF_D1P + 64UL*N2*2);    // N2*64 bf16
constexpr size_t OFF_WB2 = alup(OFF_BMP + 64UL*N2*2);    // 9*64*32 bf16
constexpr size_t OFF_WB3 = alup(OFF_WB2 + 36864UL);      // 9*2*64*32 bf16
constexpr size_t OFF_WB4 = alup(OFF_WB3 + 73728UL);      // 9*3*64*32 bf16

// ---------------- depth mean ----------------
__global__ void k_sum(const float* __restrict__ d, float* __restrict__ ws) {
    float s = 0.f;
    for (int i = blockIdx.x*blockDim.x + threadIdx.x; i < NN; i += gridDim.x*blockDim.x)
        s += d[i];
    #pragma unroll
    for (int o = 32; o; o >>= 1) s += __shfl_down(s, o, 64);
    __shared__ float sm[4];
    int wid = threadIdx.x >> 6;
    if ((threadIdx.x & 63) == 0) sm[wid] = s;
    __syncthreads();
    if (threadIdx.x == 0) {
        float t = 0.f;
        for (int w = 0; w < (int)(blockDim.x >> 6); ++w) t += sm[w];
        atomicAdd(ws, t);
    }
}

__global__ void k_buildx(const float* __restrict__ depth, const float* __restrict__ mask,
                         const float* __restrict__ ws, float* __restrict__ x) {
    int i = blockIdx.x*blockDim.x + threadIdx.x;
    if (i >= NN) return;
    float mean = ws[0] * (1.0f/NN);
    x[i]        = (depth[i] - mean) * 10.0f;
    x[NN + i]   = mask[i];
    x[2*NN + i] = 0.f;
}

__global__ void k_scatter(const int* __restrict__ pairs, float* __restrict__ x) {
    int p = blockIdx.x*blockDim.x + threadIdx.x;
    if (p < PP) x[2*NN + pairs[2*p]] = 1.0f;
}

// ------------- weight pre-transform to MFMA A-fragment layout (bf16) -------------
// dst[((t*NCH + c)*64 + co)*32 + k] = w[co][c*32+k][t]   (t = ky*3+kx)
__global__ void k_wcvt(const float* __restrict__ w, ushort* __restrict__ dst, int NCH) {
    int e = blockIdx.x*256 + threadIdx.x;
    int total = 9*NCH*64*32;
    if (e >= total) return;
    int k  = e & 31;
    int co = (e >> 5) & 63;
    int rest = e >> 11;
    int c = rest % NCH;
    int t = rest / NCH;
    dst[e] = f2b(w[(co*(NCH*32) + c*32 + k)*9 + t]);
}

// ---------------- conv1: direct 3x3, 3ch fp32 planar -> raw fp32 [px][32] ----------------
template<int CIN, int TCO>
__global__ __launch_bounds__(64) void k_conv1(const float* __restrict__ in,
        const float* __restrict__ w, const float* __restrict__ bias,
        float* __restrict__ out) {
    int x   = blockIdx.x*64 + threadIdx.x;
    int y   = blockIdx.y;
    int co0 = blockIdx.z*TCO;
    if (x >= WW) return;
    float acc[TCO];
    #pragma unroll
    for (int c = 0; c < TCO; ++c) acc[c] = bias[co0+c];
    int  xb   = x - 1;
    bool xint = (xb >= 0) && (xb + 2 < WW);
    for (int ci = 0; ci < CIN; ++ci) {
        const float* ip = in + (long)ci*NN;
        float iv[3][3];
        #pragma unroll
        for (int dy = 0; dy < 3; ++dy) {
            int iy = y + dy - 1;
            if ((unsigned)iy < (unsigned)HH) {
                const float* rp = ip + (long)iy*WW + xb;
                if (xint) { iv[dy][0]=rp[0]; iv[dy][1]=rp[1]; iv[dy][2]=rp[2]; }
                else {
                    #pragma unroll
                    for (int dx = 0; dx < 3; ++dx) {
                        int ix = xb + dx;
                        iv[dy][dx] = ((unsigned)ix < (unsigned)WW) ? ip[(long)iy*WW+ix] : 0.f;
                    }
                }
            } else iv[dy][0]=iv[dy][1]=iv[dy][2]=0.f;
        }
        const float* wp = w + ((long)co0*CIN + ci)*9;
        #pragma unroll
        for (int c = 0; c < TCO; ++c)
            #pragma unroll
            for (int k = 0; k < 9; ++k)
                acc[c] += iv[k/3][k%3] * wp[(long)c*CIN*9 + k];
    }
    float* op = out + (size_t)(y*WW + x)*32 + co0;
    #pragma unroll
    for (int c = 0; c < TCO; ++c) op[c] = acc[c];
}

// ---------------- GN stats over packed [px][32] fp32 (layer 1, chper=2) ----------------
__global__ __launch_bounds__(256) void k_gnstats_pk(const float* __restrict__ x,
        float* __restrict__ stat, int npx) {
    int o = threadIdx.x & 3;
    float s[8], s2[8];
    #pragma unroll
    for (int j = 0; j < 8; ++j) { s[j] = 0.f; s2[j] = 0.f; }
    for (int e = blockIdx.x*256 + threadIdx.x; e < npx*4; e += gridDim.x*256) {
        int px = e >> 2;
        const float* p = x + (size_t)px*32 + o*8;
        #pragma unroll
        for (int j = 0; j < 8; ++j) { float v = p[j]; s[j] += v; s2[j] += v*v; }
    }
    float gs[4], gs2[4];
    #pragma unroll
    for (int j = 0; j < 4; ++j) { gs[j] = s[2*j]+s[2*j+1]; gs2[j] = s2[2*j]+s2[2*j+1]; }
    #pragma unroll
    for (int off = 4; off < 64; off <<= 1)
        #pragma unroll
        for (int j = 0; j < 4; ++j) {
            gs[j]  += __shfl_xor(gs[j],  off, 64);
            gs2[j] += __shfl_xor(gs2[j], off, 64);
        }
    __shared__ float sm[4][4][8];
    int wv = threadIdx.x >> 6;
    if ((threadIdx.x & 63) < 4) {
        #pragma unroll
        for (int j = 0; j < 4; ++j) { sm[wv][o][j] = gs[j]; sm[wv][o][4+j] = gs2[j]; }
    }
    __syncthreads();
    if (threadIdx.x < 32) {
        int o2 = threadIdx.x >> 3, k = threadIdx.x & 7;
        float t = sm[0][o2][k] + sm[1][o2][k] + sm[2][o2][k] + sm[3][o2][k];
        int g = o2*4 + (k & 3);
        atomicAdd(&stat[(k >> 2)*16 + g], t);
    }
}

// ---------------- GN apply + lrelu + pack: [px][CH] f32 -> [px][CH] bf16 ----------------
template<int CH, int CHPER>
__global__ void k_gnpack(const float* __restrict__ x, ushort* __restrict__ y,
                         const float* __restrict__ scale, const float* __restrict__ bias,
                         const float* __restrict__ stat, int npx) {
    constexpr int PARTS = CH/16;
    int e = blockIdx.x*256 + threadIdx.x;
    if (e >= npx*PARTS) return;
    int px   = e / PARTS;
    int part = e - px*PARTS;
    const float* p = x + (size_t)px*CH + part*16;
    ushort*      q = y + (size_t)px*CH + part*16;
    float cnt = (float)CHPER * (float)npx;
    #pragma unroll
    for (int j = 0; j < 16; ++j) {
        int c = part*16 + j;
        int g = c / CHPER;
        float mu  = stat[g] / cnt;
        float var = stat[16+g] / cnt - mu*mu;
        float rs  = rsqrtf(var + 1e-5f);
        float v = (p[j] - mu) * rs * scale[c] + bias[c];
        q[j] = f2b(v >= 0.f ? v : 0.2f*v);
    }
}

// ---------------- LDS-free MFMA implicit-GEMM 3x3 conv ----------------
// MODE 2: conv2 32->64 stride2 (C1P 480x600x32 -> 240x300x64)
// MODE 3: conv3 64->64        (D1P 240x300x64 -> 240x300x64)
// MODE 4: conv4 96->64        (up2x(BMP 240x300x64) ++ C1P 480x600x32 -> 480x600x64)
// Block 256 = 4 waves; wave = 1 out row; tile 4 rows x 64 px x 64 co.
// B fragment = direct 16B global load from packed [px][ci]; A = weights in frag layout.
// Raw fp32 [px][co] output + fused GN stats (chper=4).
template<int MODE>
__global__ __launch_bounds__(256) void k_mconv(const ushort* __restrict__ inA,
        const ushort* __restrict__ inB, const ushort* __restrict__ wb,
        const float* __restrict__ bias, float* __restrict__ out,
        float* __restrict__ stat) {
    constexpr int Ho  = (MODE==4) ? HH : H2;
    constexpr int Wo  = (MODE==4) ? WW : W2;
    constexpr int NCH = (MODE==2) ? 1 : (MODE==3) ? 2 : 3;
    __shared__ float sred[4][16][2];

    int w    = threadIdx.x >> 6;
    int lane = threadIdx.x & 63;
    int lm   = lane & 15;
    int lg   = lane >> 4;
    int y0   = blockIdx.y*4;
    int x0   = blockIdx.x*64;
    int y    = y0 + w;

    f32x4 acc[4][4];
    #pragma unroll
    for (int ct = 0; ct < 4; ++ct)
        #pragma unroll
        for (int pt = 0; pt < 4; ++pt) acc[ct][pt] = 0.f;

    #pragma unroll
    for (int kc = 0; kc < NCH; ++kc) {
        #pragma unroll
        for (int t = 0; t < 9; ++t) {
            const int dy = t/3, dx = t - 3*(t/3);
            const ushort* wp = wb + (size_t)((t*NCH + kc)*64)*32;
            bf16x8 a[4];
            #pragma unroll
            for (int ct = 0; ct < 4; ++ct)
                a[ct] = *(const bf16x8*)(wp + (ct*16 + lm)*32 + lg*8);
            int iy = (MODE==2) ? 2*y + dy : y + dy - 1;
            bool rowv = (unsigned)iy < (unsigned)((MODE==3) ? H2 : HH);
            #pragma unroll
            for (int pt = 0; pt < 4; ++pt) {
                int ox = x0 + pt*16 + lm;
                int ix = (MODE==2) ? 2*ox + dx : ox + dx - 1;
                bool v = rowv && ((unsigned)ix < (unsigned)((MODE==3) ? W2 : WW));
                const ushort* bp;
                if (MODE==2) {
                    bp = inA + ((size_t)iy*WW + ix)*32 + lg*8;
                } else if (MODE==3) {
                    bp = inA + ((size_t)iy*W2 + ix)*64 + kc*32 + lg*8;
                } else {
                    bp = (kc < 2) ? inA + ((size_t)(iy>>1)*W2 + (ix>>1))*64 + kc*32 + lg*8
                                  : inB + ((size_t)iy*WW + ix)*32 + lg*8;
                }
                bf16x8 b = ld_bf8(bp, v);
                #pragma unroll
                for (int ct = 0; ct < 4; ++ct)
                    acc[ct][pt] = __builtin_amdgcn_mfma_f32_16x16x32_bf16(a[ct], b, acc[ct][pt], 0, 0, 0);
            }
        }
    }

    // epilogue: bias + store [px][co] + fused GN stats (group = co>>2 = ct*4+lg)
    #pragma unroll
    for (int ct = 0; ct < 4; ++ct) {
        float s = 0.f, s2 = 0.f;
        #pragma unroll
        for (int pt = 0; pt < 4; ++pt) {
            int pxg = x0 + pt*16 + lm;
            bool vld = pxg < Wo;
            f32x4 r;
            #pragma unroll
            for (int reg = 0; reg < 4; ++reg) {
                int co = ct*16 + lg*4 + reg;
                float v = acc[ct][pt][reg] + bias[co];
                r[reg] = v;
                if (vld) { s += v; s2 += v*v; }
            }
            if (vld)
                *(f32x4*)(out + (size_t)(y*Wo + pxg)*64 + ct*16 + lg*4) = r;
        }
        #pragma unroll
        for (int o = 1; o < 16; o <<= 1) {
            s  += __shfl_xor(s,  o, 64);
            s2 += __shfl_xor(s2, o, 64);
        }
        if (lm == 0) { sred[w][ct*4+lg][0] = s; sred[w][ct*4+lg][1] = s2; }
    }
    __syncthreads();
    if (threadIdx.x < 32) {
        int g = threadIdx.x >> 1, k = threadIdx.x & 1;
        float t = sred[0][g][k] + sred[1][g][k] + sred[2][g][k] + sred[3][g][k];
        atomicAdd(&stat[k*16 + g], t);
    }
}

// ---------------- gather + GN(L4, fused) + MLP head ----------------
__global__ void k_mlp(const float* __restrict__ pose, const float* __restrict__ sd,
                      const int* __restrict__ pairs, const float* __restrict__ feats,
                      const float* __restrict__ g4s, const float* __restrict__ g4b,
                      const float* __restrict__ st4,
                      const float* __restrict__ gw, const float* __restrict__ gb,
                      const float* __restrict__ hw, const float* __restrict__ hb,
                      const float* __restrict__ ow, const float* __restrict__ ob,
                      float* __restrict__ out) {
    int wid  = threadIdx.x >> 6;
    int lane = threadIdx.x & 63;
    int t = blockIdx.x*4 + wid;
    int p = t >> 1;
    const float* pp = pose + t*8;
    float q0=pp[0], q1=pp[1], q2=pp[2], q3=pp[3];
    float f0=pp[4], f1=pp[5], f2=pp[6], tr=pp[7];
    int idx = pairs[2*p];
    float dg = sd[idx];
    float cond[15] = {q0*q0,q0*q1,q0*q2,q0*q3,q1*q1,q1*q2,q1*q3,q2*q2,q2*q3,q3*q3,
                      f0,f1,f2,tr,dg};
    float acc = gb[lane];
    #pragma unroll
    for (int k = 0; k < 15; ++k) acc += cond[k]*gw[k*64+lane];
    float gate = 1.f/(1.f+expf(-acc));
    // contiguous gather of raw conv4 row + on-the-fly GN4 + lrelu
    float raw = feats[(size_t)idx*64 + lane];
    int   g4  = lane >> 2;
    float cnt = 4.0f * (float)NN;
    float mu  = st4[g4] / cnt;
    float var = st4[16+g4] / cnt - mu*mu;
    float rs  = rsqrtf(var + 1e-5f);
    float fv  = (raw - mu) * rs * g4s[lane] + g4b[lane];
    float fg  = fv >= 0.f ? fv : 0.2f*fv;
    float h = fg*gate;
    float ss = h*h;
    #pragma unroll
    for (int o = 32; o; o >>= 1) ss += __shfl_xor(ss, o, 64);
    h *= rsqrtf(ss + 1e-8f);
    __shared__ float hs[4][64];
    hs[wid][lane] = h;
    __syncthreads();
    float a2 = hb[lane];
    #pragma unroll 8
    for (int d = 0; d < 64; ++d) a2 += hs[wid][d]*hw[d*64+lane];
    float h2 = a2 >= 0.f ? a2 : 0.2f*a2;
    float si = h2 / (1.f+expf(-h2));
    float v = si * ow[lane];
    #pragma unroll
    for (int o = 32; o; o >>= 1) v += __shfl_xor(v, o, 64);
    if (lane == 0) out[t] = v + ob[0];
}

extern "C" void kernel_launch(void* const* d_in, const int* in_sizes, int n_in,
                              void* d_out, int out_size, void* d_ws, size_t ws_size,
                              hipStream_t stream) {
    const float* depth = (const float*)d_in[0];
    const float* pose  = (const float*)d_in[1];
    const float* mask  = (const float*)d_in[2];
    const int*   pairs = (const int*)  d_in[3];
    const float* c1w = (const float*)d_in[4];  const float* c1b = (const float*)d_in[5];
    const float* g1s = (const float*)d_in[6];  const float* g1b = (const float*)d_in[7];
    const float* c2w = (const float*)d_in[8];  const float* c2b = (const float*)d_in[9];
    const float* g2s = (const float*)d_in[10]; const float* g2b = (const float*)d_in[11];
    const float* c3w = (const float*)d_in[12]; const float* c3b = (const float*)d_in[13];
    const float* g3s = (const float*)d_in[14]; const float* g3b = (const float*)d_in[15];
    const float* c4w = (const float*)d_in[16]; const float* c4b = (const float*)d_in[17];
    const float* g4s = (const float*)d_in[18]; const float* g4b = (const float*)d_in[19];
    const float* gw  = (const float*)d_in[20]; const float* gb  = (const float*)d_in[21];
    const float* hw_ = (const float*)d_in[22]; const float* hb  = (const float*)d_in[23];
    const float* ow  = (const float*)d_in[24]; const float* ob  = (const float*)d_in[25];

    char* base = (char*)d_ws;
    float*  stats = (float*) base;
    float*  X   = (float*) (base + OFF_X);
    float*  FT  = (float*) (base + OFF_FT);
    float*  C1R = FT;                          // alias: raw conv1 [px][32] in FT region
    ushort* C1P = (ushort*)(base + OFF_C1P);
    float*  D1R = (float*) (base + OFF_D1R);
    ushort* D1P = (ushort*)(base + OFF_D1P);
    ushort* BMP = (ushort*)(base + OFF_BMP);
    ushort* WB2 = (ushort*)(base + OFF_WB2);
    ushort* WB3 = (ushort*)(base + OFF_WB3);
    ushort* WB4 = (ushort*)(base + OFF_WB4);
    float* st1 = stats + 16;
    float* st2 = stats + 64;
    float* st3 = stats + 112;
    float* st4 = stats + 160;

    hipMemsetAsync(d_ws, 0, 1024, stream);

    k_sum    <<<1024, 256, 0, stream>>>(depth, stats);
    k_buildx <<<(NN+255)/256, 256, 0, stream>>>(depth, mask, stats, X);
    k_scatter<<<(PP+255)/256, 256, 0, stream>>>(pairs, X);
    k_wcvt   <<< 72, 256, 0, stream>>>(c2w, WB2, 1);
    k_wcvt   <<<144, 256, 0, stream>>>(c3w, WB3, 2);
    k_wcvt   <<<216, 256, 0, stream>>>(c4w, WB4, 3);

    // conv1: 3->32 direct -> C1R raw [px][32]
    k_conv1<3,16><<<dim3(10, HH, 2), 64, 0, stream>>>(X, c1w, c1b, C1R);
    k_gnstats_pk<<<256, 256, 0, stream>>>(C1R, st1, NN);
    k_gnpack<32,2><<<(NN*2+255)/256, 256, 0, stream>>>(C1R, C1P, g1s, g1b, st1, NN);

    // conv2: 32->64 stride2 MFMA -> D1R raw + st2
    k_mconv<2><<<dim3(5, 60), 256, 0, stream>>>(C1P, nullptr, WB2, c2b, D1R, st2);
    k_gnpack<64,4><<<(N2*4+255)/256, 256, 0, stream>>>(D1R, D1P, g2s, g2b, st2, N2);

    // conv3: 64->64 MFMA -> D1R raw (reused) + st3
    k_mconv<3><<<dim3(5, 60), 256, 0, stream>>>(D1P, nullptr, WB3, c3b, D1R, st3);
    k_gnpack<64,4><<<(N2*4+255)/256, 256, 0, stream>>>(D1R, BMP, g3s, g3b, st3, N2);

    // conv4: concat(up2(BMP), C1P) 96->64 MFMA -> FT raw + st4
    k_mconv<4><<<dim3(10, 120), 256, 0, stream>>>(BMP, C1P, WB4, c4b, FT, st4);

    // gather + GN(L4) + MLP head
    k_mlp<<<(2*PP)/4, 256, 0, stream>>>(pose, X, pairs, FT, g4s, g4b, st4,
                                        gw, gb, hw_, hb, ow, ob, (float*)d_out);
}

// Round 6
// 322.539 us; speedup vs baseline: 35.4083x; 1.1882x over previous
//
#include <hip/hip_runtime.h>
#include <math.h>

#define HH 480
#define WW 600
#define NN (HH*WW)      // 288000
#define PP 2048
#define H2 240
#define W2 300
#define N2 (H2*W2)      // 72000

typedef __bf16  bf16x8  __attribute__((ext_vector_type(8)));
typedef float   f32x4   __attribute__((ext_vector_type(4)));
typedef ushort  ushort8 __attribute__((ext_vector_type(8)));

__device__ __forceinline__ ushort f2b(float f) {
    unsigned u = __float_as_uint(f);
    unsigned r = (u + 0x7FFF + ((u >> 16) & 1)) >> 16;
    return (ushort)r;
}

// ---- workspace layout (bytes) ----
constexpr size_t alup(size_t x) { return (x + 4095) & ~(size_t)4095; }
constexpr size_t OFF_X   = 4096;                         // 3*NN fp32 planar
constexpr size_t OFF_FT  = alup(OFF_X   + 3UL*NN*4);     // NN*64 fp32 [px][co]; front aliases C1R (NN*32 f32)
constexpr size_t OFF_C1P = alup(OFF_FT  + 64UL*NN*4);    // NN*32 bf16 [px][ci]
constexpr size_t OFF_D1R = alup(OFF_C1P + 32UL*NN*2);    // N2*64 fp32 [px][co] (conv2 raw, reused conv3 raw)
constexpr size_t OFF_D1P = alup(OFF_D1R + 64UL*N2*4);    // N2*64 bf16
constexpr size_t OFF_BMP = alup(OFF_D1P + 64UL*N2*2);    // N2*64 bf16
constexpr size_t OFF_WB2 = alup(OFF_BMP + 64UL*N2*2);    // 9*64*32 bf16
constexpr size_t OFF_WB3 = alup(OFF_WB2 + 36864UL);      // 9*2*64*32 bf16
constexpr size_t OFF_WB4 = alup(OFF_WB3 + 73728UL);      // 9*3*64*32 bf16

// ---------------- depth mean ----------------
__global__ void k_sum(const float* __restrict__ d, float* __restrict__ ws) {
    float s = 0.f;
    for (int i = blockIdx.x*blockDim.x + threadIdx.x; i < NN; i += gridDim.x*blockDim.x)
        s += d[i];
    #pragma unroll
    for (int o = 32; o; o >>= 1) s += __shfl_down(s, o, 64);
    __shared__ float sm[4];
    int wid = threadIdx.x >> 6;
    if ((threadIdx.x & 63) == 0) sm[wid] = s;
    __syncthreads();
    if (threadIdx.x == 0) {
        float t = 0.f;
        for (int w = 0; w < (int)(blockDim.x >> 6); ++w) t += sm[w];
        atomicAdd(ws, t);
    }
}

__global__ void k_buildx(const float* __restrict__ depth, const float* __restrict__ mask,
                         const float* __restrict__ ws, float* __restrict__ x) {
    int i = blockIdx.x*blockDim.x + threadIdx.x;
    if (i >= NN) return;
    float mean = ws[0] * (1.0f/NN);
    x[i]        = (depth[i] - mean) * 10.0f;
    x[NN + i]   = mask[i];
    x[2*NN + i] = 0.f;
}

__global__ void k_scatter(const int* __restrict__ pairs, float* __restrict__ x) {
    int p = blockIdx.x*blockDim.x + threadIdx.x;
    if (p < PP) x[2*NN + pairs[2*p]] = 1.0f;
}

// ------------- weight pre-transform to MFMA A-fragment layout (bf16) -------------
// dst[((t*NCH + c)*64 + co)*32 + k] = w[co][c*32+k][t]   (t = ky*3+kx)
__global__ void k_wcvt(const float* __restrict__ w, ushort* __restrict__ dst, int NCH) {
    int e = blockIdx.x*256 + threadIdx.x;
    int total = 9*NCH*64*32;
    if (e >= total) return;
    int k  = e & 31;
    int co = (e >> 5) & 63;
    int rest = e >> 11;
    int c = rest % NCH;
    int t = rest / NCH;
    dst[e] = f2b(w[(co*(NCH*32) + c*32 + k)*9 + t]);
}

// ---------------- conv1: direct 3x3, 3ch fp32 planar -> raw fp32 [px][32] ----------------
template<int CIN, int TCO>
__global__ __launch_bounds__(64) void k_conv1(const float* __restrict__ in,
        const float* __restrict__ w, const float* __restrict__ bias,
        float* __restrict__ out) {
    int x   = blockIdx.x*64 + threadIdx.x;
    int y   = blockIdx.y;
    int co0 = blockIdx.z*TCO;
    if (x >= WW) return;
    float acc[TCO];
    #pragma unroll
    for (int c = 0; c < TCO; ++c) acc[c] = bias[co0+c];
    int  xb   = x - 1;
    bool xint = (xb >= 0) && (xb + 2 < WW);
    for (int ci = 0; ci < CIN; ++ci) {
        const float* ip = in + (long)ci*NN;
        float iv[3][3];
        #pragma unroll
        for (int dy = 0; dy < 3; ++dy) {
            int iy = y + dy - 1;
            if ((unsigned)iy < (unsigned)HH) {
                const float* rp = ip + (long)iy*WW + xb;
                if (xint) { iv[dy][0]=rp[0]; iv[dy][1]=rp[1]; iv[dy][2]=rp[2]; }
                else {
                    #pragma unroll
                    for (int dx = 0; dx < 3; ++dx) {
                        int ix = xb + dx;
                        iv[dy][dx] = ((unsigned)ix < (unsigned)WW) ? ip[(long)iy*WW+ix] : 0.f;
                    }
                }
            } else iv[dy][0]=iv[dy][1]=iv[dy][2]=0.f;
        }
        const float* wp = w + ((long)co0*CIN + ci)*9;
        #pragma unroll
        for (int c = 0; c < TCO; ++c)
            #pragma unroll
            for (int k = 0; k < 9; ++k)
                acc[c] += iv[k/3][k%3] * wp[(long)c*CIN*9 + k];
    }
    float* op = out + (size_t)(y*WW + x)*32 + co0;
    #pragma unroll
    for (int c = 0; c < TCO; ++c) op[c] = acc[c];
}

// ---------------- GN stats over packed [px][32] fp32 (layer 1, chper=2) ----------------
__global__ __launch_bounds__(256) void k_gnstats_pk(const float* __restrict__ x,
        float* __restrict__ stat, int npx) {
    int o = threadIdx.x & 3;
    float s[8], s2[8];
    #pragma unroll
    for (int j = 0; j < 8; ++j) { s[j] = 0.f; s2[j] = 0.f; }
    for (int e = blockIdx.x*256 + threadIdx.x; e < npx*4; e += gridDim.x*256) {
        int px = e >> 2;
        const float* p = x + (size_t)px*32 + o*8;
        #pragma unroll
        for (int j = 0; j < 8; ++j) { float v = p[j]; s[j] += v; s2[j] += v*v; }
    }
    float gs[4], gs2[4];
    #pragma unroll
    for (int j = 0; j < 4; ++j) { gs[j] = s[2*j]+s[2*j+1]; gs2[j] = s2[2*j]+s2[2*j+1]; }
    #pragma unroll
    for (int off = 4; off < 64; off <<= 1)
        #pragma unroll
        for (int j = 0; j < 4; ++j) {
            gs[j]  += __shfl_xor(gs[j],  off, 64);
            gs2[j] += __shfl_xor(gs2[j], off, 64);
        }
    __shared__ float sm[4][4][8];
    int wv = threadIdx.x >> 6;
    if ((threadIdx.x & 63) < 4) {
        #pragma unroll
        for (int j = 0; j < 4; ++j) { sm[wv][o][j] = gs[j]; sm[wv][o][4+j] = gs2[j]; }
    }
    __syncthreads();
    if (threadIdx.x < 32) {
        int o2 = threadIdx.x >> 3, k = threadIdx.x & 7;
        float t = sm[0][o2][k] + sm[1][o2][k] + sm[2][o2][k] + sm[3][o2][k];
        int g = o2*4 + (k & 3);
        atomicAdd(&stat[(k >> 2)*16 + g], t);
    }
}

// ---------------- GN apply + lrelu + pack: [px][CH] f32 -> [px][CH] bf16 ----------------
template<int CH, int CHPER>
__global__ void k_gnpack(const float* __restrict__ x, ushort* __restrict__ y,
                         const float* __restrict__ scale, const float* __restrict__ bias,
                         const float* __restrict__ stat, int npx) {
    constexpr int PARTS = CH/16;
    int e = blockIdx.x*256 + threadIdx.x;
    if (e >= npx*PARTS) return;
    int px   = e / PARTS;
    int part = e - px*PARTS;
    const float* p = x + (size_t)px*CH + part*16;
    ushort*      q = y + (size_t)px*CH + part*16;
    float cnt = (float)CHPER * (float)npx;
    #pragma unroll
    for (int j = 0; j < 16; ++j) {
        int c = part*16 + j;
        int g = c / CHPER;
        float mu  = stat[g] / cnt;
        float var = stat[16+g] / cnt - mu*mu;
        float rs  = rsqrtf(var + 1e-5f);
        float v = (p[j] - mu) * rs * scale[c] + bias[c];
        q[j] = f2b(v >= 0.f ? v : 0.2f*v);
    }
}

// ---------------- LDS-staged MFMA implicit-GEMM 3x3 conv ----------------
// MODE 2: conv2 32->64 stride2 (C1P 480x600x32 -> 240x300x64), out tile 4x32
// MODE 3: conv3 64->64        (D1P 240x300x64 -> 240x300x64), out tile 4x64
// MODE 4: conv4 96->64 (up2x(BMP 64ch half-res) ++ C1P 32ch -> 480x600x64), tile 4x64
// Staging: batched coalesced 16B global loads -> ds_write_b128; LDS pitch 36ch
// (72B => <=2-way bank aliasing, free). B frag = ds_read_b128 with per-thread
// base + compile-time immediate offset. GN stats fused in epilogue.
template<int MODE>
__global__ __launch_bounds__(256) void k_sconv(const ushort* __restrict__ inA,
        const ushort* __restrict__ inB, const ushort* __restrict__ wb,
        const float* __restrict__ bias, float* __restrict__ out,
        float* __restrict__ stat) {
    constexpr int Wo   = (MODE==4) ? WW : W2;
    constexpr int NCH  = (MODE==2) ? 1 : (MODE==3) ? 2 : 3;
    constexpr int NPT  = (MODE==2) ? 2 : 4;
    constexpr int ROWS = (MODE==2) ? 9 : 6;
    constexpr int PXS  = 68;
    constexpr int CPITCH = 36;
    constexpr int UNITS = ROWS*PXS*4;     // 16B staging units
    constexpr int Hi = (MODE==3) ? H2 : HH;   // input space (full-res for MODE4)
    constexpr int Wi = (MODE==3) ? W2 : WW;
    __shared__ __align__(16) ushort sh[ROWS*PXS*CPITCH];
    __shared__ float sred[4][16][2];

    int w    = threadIdx.x >> 6;
    int lane = threadIdx.x & 63;
    int lm   = lane & 15;
    int lg   = lane >> 4;
    int y0   = blockIdx.y*4;
    int x0   = blockIdx.x*(NPT*16);
    int y    = y0 + w;
    int iy0  = (MODE==2) ? 2*y0 : y0 - 1;
    int ix0  = (MODE==2) ? 2*x0 : x0 - 1;

    f32x4 acc[4][NPT];
    #pragma unroll
    for (int ct = 0; ct < 4; ++ct)
        #pragma unroll
        for (int pt = 0; pt < NPT; ++pt) acc[ct][pt] = 0.f;

    // per-lane LDS read base (bytes implicit via ushort indexing)
    int dsbase = (((MODE==2 ? 2*w*PXS + 2*lm : w*PXS + lm))*CPITCH + lg*8);

    #pragma unroll
    for (int kc = 0; kc < NCH; ++kc) {
        if (kc) __syncthreads();
        // ---- stage chunk kc ----
        #pragma unroll
        for (int u0 = 0; u0 < UNITS; u0 += 256) {
            int u = u0 + threadIdx.x;
            if (u < UNITS) {
                int r  = u / (PXS*4);
                int rm = u - r*(PXS*4);
                int px = rm >> 2;
                int q  = rm & 3;
                int iy = iy0 + r;
                int ix = ix0 + px;
                ushort8 val = {};
                if ((unsigned)iy < (unsigned)Hi && (unsigned)ix < (unsigned)Wi) {
                    const ushort* sp;
                    if (MODE==2)      sp = inA + ((size_t)iy*WW + ix)*32 + q*8;
                    else if (MODE==3) sp = inA + ((size_t)iy*W2 + ix)*64 + kc*32 + q*8;
                    else if (kc < 2)  sp = inA + ((size_t)(iy>>1)*W2 + (ix>>1))*64 + kc*32 + q*8;
                    else              sp = inB + ((size_t)iy*WW + ix)*32 + q*8;
                    val = *(const ushort8*)sp;
                }
                *(ushort8*)&sh[(r*PXS + px)*CPITCH + q*8] = val;
            }
        }
        __syncthreads();
        // ---- compute chunk kc ----
        #pragma unroll
        for (int t = 0; t < 9; ++t) {
            const int dy = t/3, dx = t - 3*(t/3);
            const ushort* wp = wb + (size_t)((t*NCH + kc)*64)*32;
            bf16x8 a[4];
            #pragma unroll
            for (int ct = 0; ct < 4; ++ct)
                a[ct] = *(const bf16x8*)(wp + (ct*16 + lm)*32 + lg*8);
            #pragma unroll
            for (int pt = 0; pt < NPT; ++pt) {
                int off = (dy*PXS + (MODE==2 ? pt*32 + dx : pt*16 + dx))*CPITCH;
                bf16x8 b = *(const bf16x8*)&sh[dsbase + off];
                #pragma unroll
                for (int ct = 0; ct < 4; ++ct)
                    acc[ct][pt] = __builtin_amdgcn_mfma_f32_16x16x32_bf16(a[ct], b, acc[ct][pt], 0, 0, 0);
            }
        }
    }

    // ---- epilogue: bias + store [px][co] f32 + fused GN stats (group = ct*4+lg) ----
    #pragma unroll
    for (int ct = 0; ct < 4; ++ct) {
        float s = 0.f, s2 = 0.f;
        #pragma unroll
        for (int pt = 0; pt < NPT; ++pt) {
            int pxg = x0 + pt*16 + lm;
            bool vld = pxg < Wo;
            f32x4 r;
            #pragma unroll
            for (int reg = 0; reg < 4; ++reg) {
                int co = ct*16 + lg*4 + reg;
                float v = acc[ct][pt][reg] + bias[co];
                r[reg] = v;
                if (vld) { s += v; s2 += v*v; }
            }
            if (vld)
                *(f32x4*)(out + (size_t)(y*Wo + pxg)*64 + ct*16 + lg*4) = r;
        }
        #pragma unroll
        for (int o = 1; o < 16; o <<= 1) {
            s  += __shfl_xor(s,  o, 64);
            s2 += __shfl_xor(s2, o, 64);
        }
        if (lm == 0) { sred[w][ct*4+lg][0] = s; sred[w][ct*4+lg][1] = s2; }
    }
    __syncthreads();
    if (threadIdx.x < 32) {
        int g = threadIdx.x >> 1, k = threadIdx.x & 1;
        float t = sred[0][g][k] + sred[1][g][k] + sred[2][g][k] + sred[3][g][k];
        atomicAdd(&stat[k*16 + g], t);
    }
}

// ---------------- gather + GN(L4, fused) + MLP head ----------------
__global__ void k_mlp(const float* __restrict__ pose, const float* __restrict__ sd,
                      const int* __restrict__ pairs, const float* __restrict__ feats,
                      const float* __restrict__ g4s, const float* __restrict__ g4b,
                      const float* __restrict__ st4,
                      const float* __restrict__ gw, const float* __restrict__ gb,
                      const float* __restrict__ hw, const float* __restrict__ hb,
                      const float* __restrict__ ow, const float* __restrict__ ob,
                      float* __restrict__ out) {
    int wid  = threadIdx.x >> 6;
    int lane = threadIdx.x & 63;
    int t = blockIdx.x*4 + wid;
    int p = t >> 1;
    const float* pp = pose + t*8;
    float q0=pp[0], q1=pp[1], q2=pp[2], q3=pp[3];
    float f0=pp[4], f1=pp[5], f2=pp[6], tr=pp[7];
    int idx = pairs[2*p];
    float dg = sd[idx];
    float cond[15] = {q0*q0,q0*q1,q0*q2,q0*q3,q1*q1,q1*q2,q1*q3,q2*q2,q2*q3,q3*q3,
                      f0,f1,f2,tr,dg};
    float acc = gb[lane];
    #pragma unroll
    for (int k = 0; k < 15; ++k) acc += cond[k]*gw[k*64+lane];
    float gate = 1.f/(1.f+expf(-acc));
    float raw = feats[(size_t)idx*64 + lane];
    int   g4  = lane >> 2;
    float cnt = 4.0f * (float)NN;
    float mu  = st4[g4] / cnt;
    float var = st4[16+g4] / cnt - mu*mu;
    float rs  = rsqrtf(var + 1e-5f);
    float fv  = (raw - mu) * rs * g4s[lane] + g4b[lane];
    float fg  = fv >= 0.f ? fv : 0.2f*fv;
    float h = fg*gate;
    float ss = h*h;
    #pragma unroll
    for (int o = 32; o; o >>= 1) ss += __shfl_xor(ss, o, 64);
    h *= rsqrtf(ss + 1e-8f);
    __shared__ float hs[4][64];
    hs[wid][lane] = h;
    __syncthreads();
    float a2 = hb[lane];
    #pragma unroll 8
    for (int d = 0; d < 64; ++d) a2 += hs[wid][d]*hw[d*64+lane];
    float h2 = a2 >= 0.f ? a2 : 0.2f*a2;
    float si = h2 / (1.f+expf(-h2));
    float v = si * ow[lane];
    #pragma unroll
    for (int o = 32; o; o >>= 1) v += __shfl_xor(v, o, 64);
    if (lane == 0) out[t] = v + ob[0];
}

extern "C" void kernel_launch(void* const* d_in, const int* in_sizes, int n_in,
                              void* d_out, int out_size, void* d_ws, size_t ws_size,
                              hipStream_t stream) {
    const float* depth = (const float*)d_in[0];
    const float* pose  = (const float*)d_in[1];
    const float* mask  = (const float*)d_in[2];
    const int*   pairs = (const int*)  d_in[3];
    const float* c1w = (const float*)d_in[4];  const float* c1b = (const float*)d_in[5];
    const float* g1s = (const float*)d_in[6];  const float* g1b = (const float*)d_in[7];
    const float* c2w = (const float*)d_in[8];  const float* c2b = (const float*)d_in[9];
    const float* g2s = (const float*)d_in[10]; const float* g2b = (const float*)d_in[11];
    const float* c3w = (const float*)d_in[12]; const float* c3b = (const float*)d_in[13];
    const float* g3s = (const float*)d_in[14]; const float* g3b = (const float*)d_in[15];
    const float* c4w = (const float*)d_in[16]; const float* c4b = (const float*)d_in[17];
    const float* g4s = (const float*)d_in[18]; const float* g4b = (const float*)d_in[19];
    const float* gw  = (const float*)d_in[20]; const float* gb  = (const float*)d_in[21];
    const float* hw_ = (const float*)d_in[22]; const float* hb  = (const float*)d_in[23];
    const float* ow  = (const float*)d_in[24]; const float* ob  = (const float*)d_in[25];

    char* base = (char*)d_ws;
    float*  stats = (float*) base;
    float*  X   = (float*) (base + OFF_X);
    float*  FT  = (float*) (base + OFF_FT);
    float*  C1R = FT;                          // alias: raw conv1 [px][32] in FT region
    ushort* C1P = (ushort*)(base + OFF_C1P);
    float*  D1R = (float*) (base + OFF_D1R);
    ushort* D1P = (ushort*)(base + OFF_D1P);
    ushort* BMP = (ushort*)(base + OFF_BMP);
    ushort* WB2 = (ushort*)(base + OFF_WB2);
    ushort* WB3 = (ushort*)(base + OFF_WB3);
    ushort* WB4 = (ushort*)(base + OFF_WB4);
    float* st1 = stats + 16;
    float* st2 = stats + 64;
    float* st3 = stats + 112;
    float* st4 = stats + 160;

    hipMemsetAsync(d_ws, 0, 1024, stream);

    k_sum    <<<1024, 256, 0, stream>>>(depth, stats);
    k_buildx <<<(NN+255)/256, 256, 0, stream>>>(depth, mask, stats, X);
    k_scatter<<<(PP+255)/256, 256, 0, stream>>>(pairs, X);
    k_wcvt   <<< 72, 256, 0, stream>>>(c2w, WB2, 1);
    k_wcvt   <<<144, 256, 0, stream>>>(c3w, WB3, 2);
    k_wcvt   <<<216, 256, 0, stream>>>(c4w, WB4, 3);

    // conv1: 3->32 direct -> C1R raw [px][32]
    k_conv1<3,16><<<dim3(10, HH, 2), 64, 0, stream>>>(X, c1w, c1b, C1R);
    k_gnstats_pk<<<256, 256, 0, stream>>>(C1R, st1, NN);
    k_gnpack<32,2><<<(NN*2+255)/256, 256, 0, stream>>>(C1R, C1P, g1s, g1b, st1, NN);

    // conv2: 32->64 stride2 MFMA -> D1R raw + st2
    k_sconv<2><<<dim3(10, 60), 256, 0, stream>>>(C1P, nullptr, WB2, c2b, D1R, st2);
    k_gnpack<64,4><<<(N2*4+255)/256, 256, 0, stream>>>(D1R, D1P, g2s, g2b, st2, N2);

    // conv3: 64->64 MFMA -> D1R raw (reused) + st3
    k_sconv<3><<<dim3(5, 60), 256, 0, stream>>>(D1P, nullptr, WB3, c3b, D1R, st3);
    k_gnpack<64,4><<<(N2*4+255)/256, 256, 0, stream>>>(D1R, BMP, g3s, g3b, st3, N2);

    // conv4: concat(up2(BMP), C1P) 96->64 MFMA -> FT raw + st4
    k_sconv<4><<<dim3(10, 120), 256, 0, stream>>>(BMP, C1P, WB4, c4b, FT, st4);

    // gather + GN(L4) + MLP head
    k_mlp<<<(2*PP)/4, 256, 0, stream>>>(pose, X, pairs, FT, g4s, g4b, st4,
                                        gw, gb, hw_, hb, ow, ob, (float*)d_out);
}